// Round 6
// baseline (230.561 us; speedup 1.0000x reference)
//
#include <hip/hip_runtime.h>
#include <hip/hip_bf16.h>
#include <hip/hip_fp16.h>

#define NNODES 50000
#define NEG_SLOPE 0.2f
#define BKT_SHIFT 8
#define NBKT ((NNODES + 255) >> 8)   // 196 buckets of 256 dsts
#define STRIDE 5120                   // fixed slots per bucket (avg 4082, +16 sigma)
#define PCHUNK 2048                   // partition chunk (256 thr x 8 edges)
#define PEPT 8

typedef _Float16 half8 __attribute__((ext_vector_type(8)));
typedef float v4f __attribute__((ext_vector_type(4)));

__device__ __forceinline__ int rfl(int v) { return __builtin_amdgcn_readfirstlane(v); }

// pack W[K][C] fp32 into MFMA B-fragment order
__device__ __forceinline__ void pack_one(const float* W, _Float16* Wp, int K, int C, int tid) {
    int KC = K / 32;
    int l = tid & 63;
    int kc = (tid >> 6) % KC;
    int t = tid / (KC * 64);
    int cc = l & 15, q = l >> 4;
    half8 b;
#pragma unroll
    for (int j = 0; j < 8; j++)
        b[j] = (_Float16)W[(size_t)(kc * 32 + q * 8 + j) * C + t * 16 + cc];
    *(half8*)(Wp + (size_t)tid * 8) = b;
}

// ---------------- Kernel P: edge partition + pack W0 + pack W2 (independent) ----
__global__ __launch_bounds__(256) void kernelP(
    const int* __restrict__ src, const int* __restrict__ dst,
    int* __restrict__ bcursor, int2* __restrict__ ebuf,
    const float* __restrict__ W0, _Float16* __restrict__ Wp0,
    const float* __restrict__ W2, _Float16* __restrict__ Wp2,
    int E, int nch) {
    int blk = blockIdx.x;
    if (blk >= nch + 4) {
        // pack W2 (64 -> 128): KC=2, 8 col-tiles -> 1024 tids
        int tid = (blk - nch - 4) * 256 + threadIdx.x;
        if (tid < 8 * 2 * 64) pack_one(W2, Wp2, 64, 128, tid);
        return;
    }
    if (blk >= nch) {
        // pack W0 (128 -> 64): KC=4, 4 col-tiles -> 1024 tids
        int tid = (blk - nch) * 256 + threadIdx.x;
        if (tid < 4 * 4 * 64) pack_one(W0, Wp0, 128, 64, tid);
        return;
    }
    // ---- partition branch ----
    __shared__ int hist[NBKT];
    __shared__ int gbase[NBKT];
    int t = threadIdx.x;
    for (int i = t; i < NBKT; i += 256) hist[i] = 0;
    __syncthreads();
    int base = blk * PCHUNK;
    int sreg[PEPT], dreg[PEPT], rreg[PEPT], breg[PEPT];
#pragma unroll
    for (int k = 0; k < PEPT; k++) {
        int i = base + k * 256 + t;
        if (i < E) {
            sreg[k] = src[i];
            dreg[k] = dst[i];
            breg[k] = dreg[k] >> BKT_SHIFT;
            rreg[k] = atomicAdd(&hist[breg[k]], 1);
        } else {
            breg[k] = -1;
        }
    }
    __syncthreads();
    for (int i = t; i < NBKT; i += 256)
        if (hist[i]) gbase[i] = i * STRIDE + atomicAdd(&bcursor[i * 16], hist[i]);
    __syncthreads();
#pragma unroll
    for (int k = 0; k < PEPT; k++) {
        if (breg[k] >= 0)
            ebuf[(size_t)(gbase[breg[k]] + rreg[k])] = make_int2(sreg[k], dreg[k]);
    }
}

// ---------------- Kernel AB2: local_sort (blocks 0..NBKT) || gemm0 (rest) ----
// Sort depends only on kernelP's partition; gemm0 only on x/Wp0. Sort blocks
// come first in the grid so they dispatch immediately and hide under gemm0.
__global__ __launch_bounds__(256) void kernelAB2(
    const float* __restrict__ x, const _Float16* __restrict__ Wp0,
    const float* __restrict__ AL, const float* __restrict__ AR,
    _Float16* __restrict__ featA, float2* __restrict__ el2A, float2* __restrict__ er2A,
    const int2* __restrict__ ebuf, const int* __restrict__ bcursor,
    int2* __restrict__ rowse, int* __restrict__ csrc, int N) {
    int blk = blockIdx.x;
    if (blk < NBKT) {
        // ---- local sort branch (256 threads) ----
        __shared__ int lcnt[256], lrow[256], ws[4];
        int b = blk;
        int d0 = b << BKT_SHIFT;
        int t = threadIdx.x;
        int base = b * STRIDE;
        int endE = base + bcursor[b * 16];
        lcnt[t] = 0;
        __syncthreads();
        for (int i = base + t; i < endE; i += 256)
            atomicAdd(&lcnt[ebuf[i].y - d0], 1);
        __syncthreads();
        int v = lcnt[t];
        int lane = t & 63;
        int xx = v;
#pragma unroll
        for (int m = 1; m < 64; m <<= 1) {
            int y = __shfl_up(xx, m, 64);
            if (lane >= m) xx += y;
        }
        if (lane == 63) ws[t >> 6] = xx;
        __syncthreads();
        int w = t >> 6, waveoff = 0;
#pragma unroll
        for (int k = 0; k < 4; k++) if (k < w) waveoff += ws[k];
        int excl = base + waveoff + xx - v;
        lrow[t] = excl;
        int d = d0 + t;
        if (d < N) rowse[d] = make_int2(excl, excl + v);
        lcnt[t] = 0;
        __syncthreads();
        for (int i = base + t; i < endE; i += 256) {
            int2 e = ebuf[i];
            int ld = e.y - d0;
            int p = lrow[ld] + atomicAdd(&lcnt[ld], 1);
            csrc[p] = e.x;
        }
        return;
    }
    // ---- gemm0 branch: x fp32 hi/lo split, PACKED W0 fragments ----
    int wave = threadIdx.x >> 6, lane = threadIdx.x & 63;
    int mtile = (blk - NBKT) * 4 + wave;
    if (mtile * 16 >= N) return;
    int m0 = mtile * 16;
    int c = lane & 15, q = lane >> 4;
    v4f acc[4];
#pragma unroll
    for (int t = 0; t < 4; t++) acc[t] = (v4f){0.f, 0.f, 0.f, 0.f};
    const size_t arow = (size_t)(m0 + c) * 128 + q * 8;
#pragma unroll
    for (int kc = 0; kc < 4; kc++) {
        const float* xr = x + arow + kc * 32;
        float4 f0 = *(const float4*)xr;
        float4 f1 = *(const float4*)(xr + 4);
        float fv[8] = {f0.x, f0.y, f0.z, f0.w, f1.x, f1.y, f1.z, f1.w};
        half8 ah, av;
#pragma unroll
        for (int j = 0; j < 8; j++) {
            ah[j] = (_Float16)fv[j];
            av[j] = (_Float16)(fv[j] - (float)ah[j]);
        }
#pragma unroll
        for (int tt = 0; tt < 4; tt++) {
            half8 b = *(const half8*)(Wp0 + ((size_t)(tt * 4 + kc) * 64 + lane) * 8);
            acc[tt] = __builtin_amdgcn_mfma_f32_16x16x32_f16(ah, b, acc[tt], 0, 0, 0);
            acc[tt] = __builtin_amdgcn_mfma_f32_16x16x32_f16(av, b, acc[tt], 0, 0, 0);
        }
    }
#pragma unroll
    for (int tt = 0; tt < 4; tt++)
#pragma unroll
        for (int r = 0; r < 4; r++) {
            int row = m0 + q * 4 + r;
            featA[(size_t)row * 64 + tt * 16 + c] = (_Float16)acc[tt][r];
        }
    float alv[4], arv[4];
#pragma unroll
    for (int tt = 0; tt < 4; tt++) { alv[tt] = AL[tt * 16 + c]; arv[tt] = AR[tt * 16 + c]; }
#pragma unroll
    for (int r = 0; r < 4; r++) {
        float l0 = 0.f, l1 = 0.f, r0 = 0.f, r1 = 0.f;
#pragma unroll
        for (int tt = 0; tt < 4; tt++) {
            float v = acc[tt][r];
            if (tt < 2) { l0 = fmaf(v, alv[tt], l0); r0 = fmaf(v, arv[tt], r0); }
            else        { l1 = fmaf(v, alv[tt], l1); r1 = fmaf(v, arv[tt], r1); }
        }
#pragma unroll
        for (int m = 1; m < 16; m <<= 1) {
            l0 += __shfl_xor(l0, m, 64);
            l1 += __shfl_xor(l1, m, 64);
            r0 += __shfl_xor(r0, m, 64);
            r1 += __shfl_xor(r1, m, 64);
        }
        if (c == 0) {
            int row = m0 + q * 4 + r;
            el2A[row] = make_float2(l0, l1);
            er2A[row] = make_float2(r0, r1);
        }
    }
}

// ---------------- agg0 + fused fp32 matvec gemm1 (64->64) + layer-1 logits ----
// SPLIT staging (r5): stS early (csrc-only), stX/stY late (el2+exp).
__global__ __launch_bounds__(256) void agg0_gemm1(
    const int2* __restrict__ rowse, const int* __restrict__ csrc,
    const float2* __restrict__ el2A, const float2* __restrict__ er2A,
    const _Float16* __restrict__ featA, const float* __restrict__ b0,
    const float* __restrict__ W1, const float* __restrict__ al1, const float* __restrict__ ar1,
    _Float16* __restrict__ featB, float2* __restrict__ el2B, float2* __restrict__ er2B,
    int N) {
    __shared__ __attribute__((aligned(16))) int   stS[4][64];
    __shared__ __attribute__((aligned(16))) float stX[4][64], stY[4][64];
    __shared__ float vbuf[4][64];
    __shared__ float4 w1v[16 * 64];   // [k4][lane] -> (W1[4k4+0..3][lane])
    int wave = threadIdx.x >> 6, lane = threadIdx.x & 63, h = lane >> 5;
    for (int i = threadIdx.x; i < 64 * 64; i += 256) {
        int k = i >> 6, cc = i & 63;
        ((float*)w1v)[((((k >> 2) << 6) + cc) << 2) | (k & 3)] = W1[i];
    }
    __syncthreads();
    float bl = b0[lane];
    float al1v = al1[lane], ar1v = ar1[lane];
    const int*   stSw = stS[wave];
    const float* stWH = h ? stY[wave] : stX[wave];
    for (int n0 = blockIdx.x * 4 + wave; n0 < N; n0 += gridDim.x * 4) {
        int n = rfl(n0);
        int2 se = rowse[n];
        int beg = rfl(se.x), end = rfl(se.y);
        float2 rr = er2A[n];
        float s = 0.f, acc = 0.f;
        for (int base = beg; base < end; base += 64) {
            int idx = base + lane;
            bool act = idx < end;
            int sv = act ? csrc[idx] : 0;
            stS[wave][lane] = sv;                      // early: depends only on csrc
            float wxv = 0.f, wyv = 0.f;
            if (act) {
                float2 l = el2A[sv];
                float t0 = l.x + rr.x; t0 = t0 > 0.f ? t0 : NEG_SLOPE * t0;
                float t1 = l.y + rr.y; t1 = t1 > 0.f ? t1 : NEG_SLOPE * t1;
                wxv = __expf(t0); wyv = __expf(t1);
            }
            stX[wave][lane] = wxv;                     // late: joins at FMA
            stY[wave][lane] = wyv;
            int cnt = (min(64, end - base) + 7) & ~7;  // padded: no scalar tail
            for (int j = 0; j < cnt; j += 8) {
                int4 sA = *(const int4*)(stSw + j);
                int4 sB = *(const int4*)(stSw + j + 4);
                float f0 = (float)featA[(size_t)sA.x * 64 + lane];
                float f1 = (float)featA[(size_t)sA.y * 64 + lane];
                float f2 = (float)featA[(size_t)sA.z * 64 + lane];
                float f3 = (float)featA[(size_t)sA.w * 64 + lane];
                float f4 = (float)featA[(size_t)sB.x * 64 + lane];
                float f5 = (float)featA[(size_t)sB.y * 64 + lane];
                float f6 = (float)featA[(size_t)sB.z * 64 + lane];
                float f7 = (float)featA[(size_t)sB.w * 64 + lane];
                float4 wv0 = *(const float4*)(stWH + j);
                float4 wv1 = *(const float4*)(stWH + j + 4);
                s += ((wv0.x + wv0.y) + (wv0.z + wv0.w)) + ((wv1.x + wv1.y) + (wv1.z + wv1.w));
                acc = fmaf(wv0.x, f0, acc);
                acc = fmaf(wv0.y, f1, acc);
                acc = fmaf(wv0.z, f2, acc);
                acc = fmaf(wv0.w, f3, acc);
                acc = fmaf(wv1.x, f4, acc);
                acc = fmaf(wv1.y, f5, acc);
                acc = fmaf(wv1.z, f6, acc);
                acc = fmaf(wv1.w, f7, acc);
            }
        }
        float v = (s > 0.f) ? acc / s : 0.f;
        v = fmaxf(v + bl, 0.f);
        vbuf[wave][lane] = v;
        const float4* vv = (const float4*)vbuf[wave];
        float f = 0.f;
#pragma unroll
        for (int kk = 0; kk < 16; kk++) {
            float4 v4 = vv[kk];                 // LDS broadcast (same addr all lanes)
            float4 w4 = w1v[(kk << 6) + lane];  // contiguous b128, conflict-free
            f = fmaf(v4.x, w4.x, f);
            f = fmaf(v4.y, w4.y, f);
            f = fmaf(v4.z, w4.z, f);
            f = fmaf(v4.w, w4.w, f);
        }
        featB[(size_t)n * 64 + lane] = (_Float16)f;
        float vl = f * al1v, vr = f * ar1v;
#pragma unroll
        for (int m = 1; m < 32; m <<= 1) {
            vl += __shfl_xor(vl, m, 64);
            vr += __shfl_xor(vr, m, 64);
        }
        if ((lane & 31) == 0) {
            ((float*)el2B)[n * 2 + h] = vl;
            ((float*)er2B)[n * 2 + h] = vr;
        }
    }
}

// ---------------- agg1 (layer 1), PAIRED + split staging ----
__global__ __launch_bounds__(256) void aggregate32(
    const int2* __restrict__ rowse, const int* __restrict__ csrc,
    const float2* __restrict__ el2, const float2* __restrict__ er2,
    const _Float16* __restrict__ feat16, const float* __restrict__ b,
    _Float16* __restrict__ ahi, _Float16* __restrict__ alo, int N) {
    __shared__ __attribute__((aligned(16))) int   stS0[4][64], stS1[4][64];
    __shared__ __attribute__((aligned(16))) float stX0[4][64], stY0[4][64];
    __shared__ __attribute__((aligned(16))) float stX1[4][64], stY1[4][64];
    int wave = threadIdx.x >> 6, lane = threadIdx.x & 63, h = lane >> 5;
    int g = rfl(blockIdx.x * 4 + wave);
    int n0 = 2 * g, n1 = n0 + 1;
    if (n0 >= N) return;
    bool has1 = (n1 < N);
    float bl = b[lane];
    int2 se0 = rowse[n0];
    int2 se1 = has1 ? rowse[n1] : make_int2(0, 0);
    int beg0 = rfl(se0.x), len0 = rfl(se0.y) - beg0;
    int beg1 = rfl(se1.x), len1 = rfl(se1.y) - beg1;
    float2 rr0 = er2[n0];
    float2 rr1 = has1 ? er2[n1] : make_float2(0.f, 0.f);
    const int*   stSw0 = stS0[wave];
    const int*   stSw1 = stS1[wave];
    const float* stWH0 = h ? stY0[wave] : stX0[wave];
    const float* stWH1 = h ? stY1[wave] : stX1[wave];
    float s0 = 0.f, acc0 = 0.f, s1 = 0.f, acc1 = 0.f;
    int chunks = max(len0, len1);
    for (int off = 0; off < chunks; off += 64) {
        bool a0 = off + lane < len0;
        bool a1 = off + lane < len1;
        int sv0 = a0 ? csrc[beg0 + off + lane] : 0;
        int sv1 = a1 ? csrc[beg1 + off + lane] : 0;
        stS0[wave][lane] = sv0;                  // early stores: index-only
        stS1[wave][lane] = sv1;
        float wx0 = 0.f, wy0 = 0.f, wx1 = 0.f, wy1 = 0.f;
        if (a0) {
            float2 l = el2[sv0];
            float t0 = l.x + rr0.x; t0 = t0 > 0.f ? t0 : NEG_SLOPE * t0;
            float t1 = l.y + rr0.y; t1 = t1 > 0.f ? t1 : NEG_SLOPE * t1;
            wx0 = __expf(t0); wy0 = __expf(t1);
        }
        if (a1) {
            float2 l = el2[sv1];
            float t0 = l.x + rr1.x; t0 = t0 > 0.f ? t0 : NEG_SLOPE * t0;
            float t1 = l.y + rr1.y; t1 = t1 > 0.f ? t1 : NEG_SLOPE * t1;
            wx1 = __expf(t0); wy1 = __expf(t1);
        }
        stX0[wave][lane] = wx0; stY0[wave][lane] = wy0;
        stX1[wave][lane] = wx1; stY1[wave][lane] = wy1;
        int cnt = (min(64, chunks - off) + 7) & ~7;
        for (int j = 0; j < cnt; j += 8) {
            int4 sA = *(const int4*)(stSw0 + j);
            int4 sB = *(const int4*)(stSw0 + j + 4);
            int4 tA = *(const int4*)(stSw1 + j);
            int4 tB = *(const int4*)(stSw1 + j + 4);
            float f0 = (float)feat16[(size_t)sA.x * 64 + lane];
            float f1 = (float)feat16[(size_t)sA.y * 64 + lane];
            float f2 = (float)feat16[(size_t)sA.z * 64 + lane];
            float f3 = (float)feat16[(size_t)sA.w * 64 + lane];
            float f4 = (float)feat16[(size_t)sB.x * 64 + lane];
            float f5 = (float)feat16[(size_t)sB.y * 64 + lane];
            float f6 = (float)feat16[(size_t)sB.z * 64 + lane];
            float f7 = (float)feat16[(size_t)sB.w * 64 + lane];
            float p0 = (float)feat16[(size_t)tA.x * 64 + lane];
            float p1 = (float)feat16[(size_t)tA.y * 64 + lane];
            float p2 = (float)feat16[(size_t)tA.z * 64 + lane];
            float p3 = (float)feat16[(size_t)tA.w * 64 + lane];
            float p4 = (float)feat16[(size_t)tB.x * 64 + lane];
            float p5 = (float)feat16[(size_t)tB.y * 64 + lane];
            float p6 = (float)feat16[(size_t)tB.z * 64 + lane];
            float p7 = (float)feat16[(size_t)tB.w * 64 + lane];
            float4 wv0 = *(const float4*)(stWH0 + j);
            float4 wv1 = *(const float4*)(stWH0 + j + 4);
            float4 xv0 = *(const float4*)(stWH1 + j);
            float4 xv1 = *(const float4*)(stWH1 + j + 4);
            s0 += ((wv0.x + wv0.y) + (wv0.z + wv0.w)) + ((wv1.x + wv1.y) + (wv1.z + wv1.w));
            acc0 = fmaf(wv0.x, f0, acc0);
            acc0 = fmaf(wv0.y, f1, acc0);
            acc0 = fmaf(wv0.z, f2, acc0);
            acc0 = fmaf(wv0.w, f3, acc0);
            acc0 = fmaf(wv1.x, f4, acc0);
            acc0 = fmaf(wv1.y, f5, acc0);
            acc0 = fmaf(wv1.z, f6, acc0);
            acc0 = fmaf(wv1.w, f7, acc0);
            s1 += ((xv0.x + xv0.y) + (xv0.z + xv0.w)) + ((xv1.x + xv1.y) + (xv1.z + xv1.w));
            acc1 = fmaf(xv0.x, p0, acc1);
            acc1 = fmaf(xv0.y, p1, acc1);
            acc1 = fmaf(xv0.z, p2, acc1);
            acc1 = fmaf(xv0.w, p3, acc1);
            acc1 = fmaf(xv1.x, p4, acc1);
            acc1 = fmaf(xv1.y, p5, acc1);
            acc1 = fmaf(xv1.z, p6, acc1);
            acc1 = fmaf(xv1.w, p7, acc1);
        }
    }
    float v = (s0 > 0.f) ? acc0 / s0 : 0.f;
    v = fmaxf(v + bl, 0.f);
    _Float16 hv = (_Float16)v;
    ahi[(size_t)n0 * 64 + lane] = hv;
    alo[(size_t)n0 * 64 + lane] = (_Float16)(v - (float)hv);
    if (has1) {
        float u = (s1 > 0.f) ? acc1 / s1 : 0.f;
        u = fmaxf(u + bl, 0.f);
        _Float16 hu = (_Float16)u;
        ahi[(size_t)n1 * 64 + lane] = hu;
        alo[(size_t)n1 * 64 + lane] = (_Float16)(u - (float)hu);
    }
}

// ---------------- gemm2: MFMA 64->128, half2-interleaved feat + layer-2 logits ----
__global__ __launch_bounds__(256) void gemm_mfma2(
    const _Float16* __restrict__ Ahi, const _Float16* __restrict__ Alo,
    const _Float16* __restrict__ Wp,
    const float* __restrict__ AL, const float* __restrict__ AR,
    __half2* __restrict__ feat2, float2* __restrict__ el2, float2* __restrict__ er2,
    int N) {
    constexpr int KC = 2, NT = 8;
    int wave = threadIdx.x >> 6, lane = threadIdx.x & 63;
    int mtile = blockIdx.x * 4 + wave;
    if (mtile * 16 >= N) return;
    int m0 = mtile * 16;
    int c = lane & 15, q = lane >> 4;
    v4f acc[NT];
#pragma unroll
    for (int t = 0; t < NT; t++) acc[t] = (v4f){0.f, 0.f, 0.f, 0.f};
    const size_t arow = (size_t)(m0 + c) * 64 + q * 8;
#pragma unroll
    for (int kc = 0; kc < KC; kc++) {
        half8 ah = *(const half8*)(Ahi + arow + kc * 32);
        half8 av = *(const half8*)(Alo + arow + kc * 32);
#pragma unroll
        for (int t = 0; t < NT; t++) {
            half8 b = *(const half8*)(Wp + ((size_t)(t * KC + kc) * 64 + lane) * 8);
            acc[t] = __builtin_amdgcn_mfma_f32_16x16x32_f16(ah, b, acc[t], 0, 0, 0);
            acc[t] = __builtin_amdgcn_mfma_f32_16x16x32_f16(av, b, acc[t], 0, 0, 0);
        }
    }
#pragma unroll
    for (int t = 0; t < NT / 2; t++)
#pragma unroll
        for (int r = 0; r < 4; r++) {
            int row = m0 + q * 4 + r;
            feat2[(size_t)row * 64 + t * 16 + c] =
                __floats2half2_rn(acc[t][r], acc[t + NT / 2][r]);
        }
    float alv[NT], arv[NT];
#pragma unroll
    for (int t = 0; t < NT; t++) { alv[t] = AL[t * 16 + c]; arv[t] = AR[t * 16 + c]; }
#pragma unroll
    for (int r = 0; r < 4; r++) {
        float l0 = 0.f, l1 = 0.f, r0 = 0.f, r1 = 0.f;
#pragma unroll
        for (int t = 0; t < NT; t++) {
            float v = acc[t][r];
            if (t < NT / 2) { l0 = fmaf(v, alv[t], l0); r0 = fmaf(v, arv[t], r0); }
            else            { l1 = fmaf(v, alv[t], l1); r1 = fmaf(v, arv[t], r1); }
        }
#pragma unroll
        for (int m = 1; m < 16; m <<= 1) {
            l0 += __shfl_xor(l0, m, 64);
            l1 += __shfl_xor(l1, m, 64);
            r0 += __shfl_xor(r0, m, 64);
            r1 += __shfl_xor(r1, m, 64);
        }
        if (c == 0) {
            int row = m0 + q * 4 + r;
            el2[row] = make_float2(l0, l1);
            er2[row] = make_float2(r0, r1);
        }
    }
}

// ---------------- agg2 PAIRED + split staging; mean over heads ----------------
__global__ __launch_bounds__(256) void aggregate64_mean(
    const int2* __restrict__ rowse, const int* __restrict__ csrc,
    const float2* __restrict__ el2, const float2* __restrict__ er2,
    const __half2* __restrict__ feat2, const float* __restrict__ b,
    float* __restrict__ out, int N) {
    __shared__ __attribute__((aligned(16))) int   stS0[4][64], stS1[4][64];
    __shared__ __attribute__((aligned(16))) float stX0[4][64], stY0[4][64];
    __shared__ __attribute__((aligned(16))) float stX1[4][64], stY1[4][64];
    int wave = threadIdx.x >> 6, lane = threadIdx.x & 63;
    int g = rfl(blockIdx.x * 4 + wave);
    int n0 = 2 * g, n1 = n0 + 1;
    if (n0 >= N) return;
    bool has1 = (n1 < N);
    float b0v = b[lane], b1v = b[64 + lane];
    int2 se0 = rowse[n0];
    int2 se1 = has1 ? rowse[n1] : make_int2(0, 0);
    int beg0 = rfl(se0.x), len0 = rfl(se0.y) - beg0;
    int beg1 = rfl(se1.x), len1 = rfl(se1.y) - beg1;
    float2 rr0 = er2[n0];
    float2 rr1 = has1 ? er2[n1] : make_float2(0.f, 0.f);
    const int* stSw0 = stS0[wave];
    const int* stSw1 = stS1[wave];
    float s00 = 0.f, s01 = 0.f, a00 = 0.f, a01 = 0.f;
    float s10 = 0.f, s11 = 0.f, a10 = 0.f, a11 = 0.f;
    int chunks = max(len0, len1);
    for (int off = 0; off < chunks; off += 64) {
        bool a0 = off + lane < len0;
        bool a1 = off + lane < len1;
        int sv0 = a0 ? csrc[beg0 + off + lane] : 0;
        int sv1 = a1 ? csrc[beg1 + off + lane] : 0;
        stS0[wave][lane] = sv0;
        stS1[wave][lane] = sv1;
        float wx0 = 0.f, wy0 = 0.f, wx1 = 0.f, wy1 = 0.f;
        if (a0) {
            float2 l = el2[sv0];
            float t0 = l.x + rr0.x; t0 = t0 > 0.f ? t0 : NEG_SLOPE * t0;
            float t1 = l.y + rr0.y; t1 = t1 > 0.f ? t1 : NEG_SLOPE * t1;
            wx0 = __expf(t0); wy0 = __expf(t1);
        }
        if (a1) {
            float2 l = el2[sv1];
            float t0 = l.x + rr1.x; t0 = t0 > 0.f ? t0 : NEG_SLOPE * t0;
            float t1 = l.y + rr1.y; t1 = t1 > 0.f ? t1 : NEG_SLOPE * t1;
            wx1 = __expf(t0); wy1 = __expf(t1);
        }
        stX0[wave][lane] = wx0; stY0[wave][lane] = wy0;
        stX1[wave][lane] = wx1; stY1[wave][lane] = wy1;
        int cnt = (min(64, chunks - off) + 7) & ~7;
        for (int j = 0; j < cnt; j += 8) {
            int4 sA = *(const int4*)(stSw0 + j);
            int4 sB = *(const int4*)(stSw0 + j + 4);
            int4 tA = *(const int4*)(stSw1 + j);
            int4 tB = *(const int4*)(stSw1 + j + 4);
            float2 fv0[8], fv1[8];
            fv0[0] = __half22float2(feat2[(size_t)sA.x * 64 + lane]);
            fv0[1] = __half22float2(feat2[(size_t)sA.y * 64 + lane]);
            fv0[2] = __half22float2(feat2[(size_t)sA.z * 64 + lane]);
            fv0[3] = __half22float2(feat2[(size_t)sA.w * 64 + lane]);
            fv0[4] = __half22float2(feat2[(size_t)sB.x * 64 + lane]);
            fv0[5] = __half22float2(feat2[(size_t)sB.y * 64 + lane]);
            fv0[6] = __half22float2(feat2[(size_t)sB.z * 64 + lane]);
            fv0[7] = __half22float2(feat2[(size_t)sB.w * 64 + lane]);
            fv1[0] = __half22float2(feat2[(size_t)tA.x * 64 + lane]);
            fv1[1] = __half22float2(feat2[(size_t)tA.y * 64 + lane]);
            fv1[2] = __half22float2(feat2[(size_t)tA.z * 64 + lane]);
            fv1[3] = __half22float2(feat2[(size_t)tA.w * 64 + lane]);
            fv1[4] = __half22float2(feat2[(size_t)tB.x * 64 + lane]);
            fv1[5] = __half22float2(feat2[(size_t)tB.y * 64 + lane]);
            fv1[6] = __half22float2(feat2[(size_t)tB.z * 64 + lane]);
            fv1[7] = __half22float2(feat2[(size_t)tB.w * 64 + lane]);
            float4 wx0v = *(const float4*)(stX0[wave] + j);
            float4 wx0w = *(const float4*)(stX0[wave] + j + 4);
            float4 wy0v = *(const float4*)(stY0[wave] + j);
            float4 wy0w = *(const float4*)(stY0[wave] + j + 4);
            float4 wx1v = *(const float4*)(stX1[wave] + j);
            float4 wx1w = *(const float4*)(stX1[wave] + j + 4);
            float4 wy1v = *(const float4*)(stY1[wave] + j);
            float4 wy1w = *(const float4*)(stY1[wave] + j + 4);
            float wxs0[8] = {wx0v.x, wx0v.y, wx0v.z, wx0v.w, wx0w.x, wx0w.y, wx0w.z, wx0w.w};
            float wys0[8] = {wy0v.x, wy0v.y, wy0v.z, wy0v.w, wy0w.x, wy0w.y, wy0w.z, wy0w.w};
            float wxs1[8] = {wx1v.x, wx1v.y, wx1v.z, wx1v.w, wx1w.x, wx1w.y, wx1w.z, wx1w.w};
            float wys1[8] = {wy1v.x, wy1v.y, wy1v.z, wy1v.w, wy1w.x, wy1w.y, wy1w.z, wy1w.w};
#pragma unroll
            for (int u = 0; u < 8; u++) {
                s00 += wxs0[u]; s01 += wys0[u];
                a00 = fmaf(wxs0[u], fv0[u].x, a00);
                a01 = fmaf(wys0[u], fv0[u].y, a01);
            }
#pragma unroll
            for (int u = 0; u < 8; u++) {
                s10 += wxs1[u]; s11 += wys1[u];
                a10 = fmaf(wxs1[u], fv1[u].x, a10);
                a11 = fmaf(wys1[u], fv1[u].y, a11);
            }
        }
    }
    float v0 = (s00 > 0.f) ? a00 / s00 : 0.f;
    float v1 = (s01 > 0.f) ? a01 / s01 : 0.f;
    out[(size_t)n0 * 64 + lane] = 0.5f * ((v0 + b0v) + (v1 + b1v));
    if (has1) {
        float u0 = (s10 > 0.f) ? a10 / s10 : 0.f;
        float u1 = (s11 > 0.f) ? a11 / s11 : 0.f;
        out[(size_t)n1 * 64 + lane] = 0.5f * ((u0 + b0v) + (u1 + b1v));
    }
}

// ---------------- launcher ----------------

extern "C" void kernel_launch(void* const* d_in, const int* in_sizes, int n_in,
                              void* d_out, int out_size, void* d_ws, size_t ws_size,
                              hipStream_t stream) {
    const float* x   = (const float*)d_in[0];
    const int*   src = (const int*)d_in[1];
    const int*   dst = (const int*)d_in[2];
    const float* W0  = (const float*)d_in[3];
    const float* al0 = (const float*)d_in[4];
    const float* ar0 = (const float*)d_in[5];
    const float* b0  = (const float*)d_in[6];
    const float* W1  = (const float*)d_in[7];
    const float* al1 = (const float*)d_in[8];
    const float* ar1 = (const float*)d_in[9];
    const float* b1  = (const float*)d_in[10];
    const float* W2  = (const float*)d_in[11];
    const float* al2 = (const float*)d_in[12];
    const float* ar2 = (const float*)d_in[13];
    const float* b2  = (const float*)d_in[14];
    float* out = (float*)d_out;

    const int N = NNODES;
    const int E = in_sizes[1];

    char* p = (char*)d_ws;
    auto alloc = [&](size_t bytes) {
        void* r = (void*)p;
        p += (bytes + 255) & ~(size_t)255;
        return r;
    };
    int*    bcursor = (int*)alloc((size_t)NBKT * 16 * 4);
    int2*   rowse   = (int2*)alloc((size_t)N * 8);
    int2*   ebuf    = (int2*)alloc(((size_t)NBKT * STRIDE + 4096) * 8);
    int*    csrc    = (int*)alloc(((size_t)NBKT * STRIDE + 4096) * 4);
    float2* el2A    = (float2*)alloc((size_t)N * 8);
    float2* er2A    = (float2*)alloc((size_t)N * 8);
    float2* el2B    = (float2*)alloc((size_t)N * 8);
    float2* er2B    = (float2*)alloc((size_t)N * 8);
    _Float16* ahi   = (_Float16*)alloc((size_t)N * 64 * 2);
    _Float16* alo   = (_Float16*)alloc((size_t)N * 64 * 2);
    void*   featA   = alloc((size_t)N * 64 * 4);
    _Float16* featB = (_Float16*)alloc((size_t)N * 64 * 2);
    _Float16* Wp2   = (_Float16*)alloc(8 * 2 * 64 * 8 * 2);
    _Float16* Wp0   = (_Float16*)alloc(4 * 4 * 64 * 8 * 2);

    // 0) zero bucket counters (partition counts from zero)
    hipMemsetAsync(bcursor, 0, (size_t)NBKT * 16 * 4, stream);
    // 1) partition + pack W0 + pack W2 (independent jobs, one launch)
    int nch = (E + PCHUNK - 1) / PCHUNK;
    kernelP<<<nch + 8, 256, 0, stream>>>(src, dst, bcursor, ebuf, W0, Wp0, W2, Wp2, E, nch);
    // 2) local_sort (depends on partition) || gemm0 (depends on x/Wp0) -- overlapped
    kernelAB2<<<NBKT + 782, 256, 0, stream>>>(x, Wp0, al0, ar0, (_Float16*)featA, el2A, er2A,
                                              ebuf, bcursor, rowse, csrc, N);
    // 3) layer-0 aggregate + fused fp32 gemm1 + layer-1 logits
    agg0_gemm1<<<2048, 256, 0, stream>>>(rowse, csrc, el2A, er2A, (const _Float16*)featA,
                                         b0, W1, al1, ar1, featB, el2B, er2B, N);
    // 4) layer-1 aggregate (PAIRED, split-stage) -> hi/lo fp16
    int npair = (N + 1) / 2;
    int nbp = (npair + 3) / 4;
    aggregate32<<<nbp, 256, 0, stream>>>(rowse, csrc, el2B, er2B, featB, b1, ahi, alo, N);
    // 5) gemm2 MFMA (64->128)
    int gb = (N / 16 + 3) / 4;
    gemm_mfma2<<<gb, 256, 0, stream>>>(ahi, alo, Wp2, al2, ar2, (__half2*)featA, el2A, er2A, N);
    // 6) layer-2 aggregate (PAIRED, split-stage), mean over heads
    aggregate64_mean<<<nbp, 256, 0, stream>>>(rowse, csrc, el2A, er2A, (const __half2*)featA,
                                              b2, out, N);
}

// Round 7
// 213.161 us; speedup vs baseline: 1.0816x; 1.0816x over previous
//
#include <hip/hip_runtime.h>
#include <hip/hip_bf16.h>
#include <hip/hip_fp16.h>

#define NNODES 50000
#define NEG_SLOPE 0.2f
#define BKT_SHIFT 8
#define NBKT ((NNODES + 255) >> 8)   // 196 buckets of 256 dsts
#define STRIDE 5120                   // fixed slots per bucket (avg 4082, +16 sigma)
#define PCHUNK 2048                   // partition chunk (256 thr x 8 edges)
#define PEPT 8

typedef _Float16 half8 __attribute__((ext_vector_type(8)));
typedef float v4f __attribute__((ext_vector_type(4)));

__device__ __forceinline__ int rfl(int v) { return __builtin_amdgcn_readfirstlane(v); }

// pack W[K][C] fp32 into MFMA B-fragment order
__device__ __forceinline__ void pack_one(const float* W, _Float16* Wp, int K, int C, int tid) {
    int KC = K / 32;
    int l = tid & 63;
    int kc = (tid >> 6) % KC;
    int t = tid / (KC * 64);
    int cc = l & 15, q = l >> 4;
    half8 b;
#pragma unroll
    for (int j = 0; j < 8; j++)
        b[j] = (_Float16)W[(size_t)(kc * 32 + q * 8 + j) * C + t * 16 + cc];
    *(half8*)(Wp + (size_t)tid * 8) = b;
}

// ---------------- Kernel AB: gemm0 + pack W2 + pack W1 + edge partition ----------
// blocks [0,782): gemm0 | [782,786): pack W2 | [786,788): pack W1 | rest: partition
// (Wp1/Wp2 consumed only by LATER kernels -> no intra-launch race.)
__global__ __launch_bounds__(256) void kernelAB(
    const float* __restrict__ x, const float* __restrict__ W0,
    const float* __restrict__ AL, const float* __restrict__ AR,
    _Float16* __restrict__ featA, float2* __restrict__ el2A, float2* __restrict__ er2A,
    const float* __restrict__ W2, _Float16* __restrict__ Wp2,
    const float* __restrict__ W1, _Float16* __restrict__ Wp1,
    const int* __restrict__ src, const int* __restrict__ dst,
    int* __restrict__ bcursor, int2* __restrict__ ebuf, int E, int N) {
    int blk = blockIdx.x;
    if (blk >= 788) {
        // ---- partition branch ----
        __shared__ int hist[NBKT];
        __shared__ int gbase[NBKT];
        int t = threadIdx.x;
        for (int i = t; i < NBKT; i += 256) hist[i] = 0;
        __syncthreads();
        int base = (blk - 788) * PCHUNK;
        int sreg[PEPT], dreg[PEPT], rreg[PEPT], breg[PEPT];
#pragma unroll
        for (int k = 0; k < PEPT; k++) {
            int i = base + k * 256 + t;
            if (i < E) {
                sreg[k] = src[i];
                dreg[k] = dst[i];
                breg[k] = dreg[k] >> BKT_SHIFT;
                rreg[k] = atomicAdd(&hist[breg[k]], 1);
            } else {
                breg[k] = -1;
            }
        }
        __syncthreads();
        for (int i = t; i < NBKT; i += 256)
            if (hist[i]) gbase[i] = i * STRIDE + atomicAdd(&bcursor[i * 16], hist[i]);
        __syncthreads();
#pragma unroll
        for (int k = 0; k < PEPT; k++) {
            if (breg[k] >= 0)
                ebuf[(size_t)(gbase[breg[k]] + rreg[k])] = make_int2(sreg[k], dreg[k]);
        }
        return;
    }
    if (blk >= 786) {
        // pack W1 (64 -> 64): KC=2, 4 col-tiles -> 512 tids
        int tid = (blk - 786) * 256 + threadIdx.x;
        if (tid < 4 * 2 * 64) pack_one(W1, Wp1, 64, 64, tid);
        return;
    }
    if (blk >= 782) {
        int tid = (blk - 782) * 256 + threadIdx.x;
        if (tid < 8 * 2 * 64) pack_one(W2, Wp2, 64, 128, tid);
        return;
    }
    // ---- gemm0 branch (scalar W0 loads; proven r5 config) ----
    int wave = threadIdx.x >> 6, lane = threadIdx.x & 63;
    int mtile = blk * 4 + wave;
    if (mtile * 16 >= N) return;
    int m0 = mtile * 16;
    int c = lane & 15, q = lane >> 4;
    v4f acc[4];
#pragma unroll
    for (int t = 0; t < 4; t++) acc[t] = (v4f){0.f, 0.f, 0.f, 0.f};
    const size_t arow = (size_t)(m0 + c) * 128 + q * 8;
#pragma unroll
    for (int kc = 0; kc < 4; kc++) {
        const float* xr = x + arow + kc * 32;
        float4 f0 = *(const float4*)xr;
        float4 f1 = *(const float4*)(xr + 4);
        float fv[8] = {f0.x, f0.y, f0.z, f0.w, f1.x, f1.y, f1.z, f1.w};
        half8 ah, av;
#pragma unroll
        for (int j = 0; j < 8; j++) {
            ah[j] = (_Float16)fv[j];
            av[j] = (_Float16)(fv[j] - (float)ah[j]);
        }
#pragma unroll
        for (int tt = 0; tt < 4; tt++) {
            half8 b;
#pragma unroll
            for (int j = 0; j < 8; j++)
                b[j] = (_Float16)W0[(size_t)(kc * 32 + q * 8 + j) * 64 + tt * 16 + c];
            acc[tt] = __builtin_amdgcn_mfma_f32_16x16x32_f16(ah, b, acc[tt], 0, 0, 0);
            acc[tt] = __builtin_amdgcn_mfma_f32_16x16x32_f16(av, b, acc[tt], 0, 0, 0);
        }
    }
#pragma unroll
    for (int tt = 0; tt < 4; tt++)
#pragma unroll
        for (int r = 0; r < 4; r++) {
            int row = m0 + q * 4 + r;
            featA[(size_t)row * 64 + tt * 16 + c] = (_Float16)acc[tt][r];
        }
    float alv[4], arv[4];
#pragma unroll
    for (int tt = 0; tt < 4; tt++) { alv[tt] = AL[tt * 16 + c]; arv[tt] = AR[tt * 16 + c]; }
#pragma unroll
    for (int r = 0; r < 4; r++) {
        float l0 = 0.f, l1 = 0.f, r0 = 0.f, r1 = 0.f;
#pragma unroll
        for (int tt = 0; tt < 4; tt++) {
            float v = acc[tt][r];
            if (tt < 2) { l0 = fmaf(v, alv[tt], l0); r0 = fmaf(v, arv[tt], r0); }
            else        { l1 = fmaf(v, alv[tt], l1); r1 = fmaf(v, arv[tt], r1); }
        }
#pragma unroll
        for (int m = 1; m < 16; m <<= 1) {
            l0 += __shfl_xor(l0, m, 64);
            l1 += __shfl_xor(l1, m, 64);
            r0 += __shfl_xor(r0, m, 64);
            r1 += __shfl_xor(r1, m, 64);
        }
        if (c == 0) {
            int row = m0 + q * 4 + r;
            el2A[row] = make_float2(l0, l1);
            er2A[row] = make_float2(r0, r1);
        }
    }
}

// ---------------- local sort: 1024 threads/bucket ----
__global__ __launch_bounds__(1024) void local_sort(const int2* __restrict__ ebuf,
                                                   const int* __restrict__ bcursor,
                                                   int2* __restrict__ rowse,
                                                   int* __restrict__ csrc, int N) {
    __shared__ int lcnt[256], lrow[256], ws[4];
    int b = blockIdx.x;
    int d0 = b << BKT_SHIFT;
    int t = threadIdx.x;
    int base = b * STRIDE;
    int endE = base + bcursor[b * 16];
    if (t < 256) lcnt[t] = 0;
    __syncthreads();
    for (int i = base + t; i < endE; i += 1024)
        atomicAdd(&lcnt[ebuf[i].y - d0], 1);
    __syncthreads();
    int v = (t < 256) ? lcnt[t] : 0;
    int lane = t & 63;
    int x = v;
#pragma unroll
    for (int m = 1; m < 64; m <<= 1) {
        int y = __shfl_up(x, m, 64);
        if (lane >= m) x += y;
    }
    if (t < 256 && lane == 63) ws[t >> 6] = x;
    __syncthreads();
    if (t < 256) {
        int w = t >> 6, waveoff = 0;
#pragma unroll
        for (int k = 0; k < 4; k++) if (k < w) waveoff += ws[k];
        int excl = base + waveoff + x - v;
        lrow[t] = excl;
        int d = d0 + t;
        if (d < N) rowse[d] = make_int2(excl, excl + v);
        lcnt[t] = 0;
    }
    __syncthreads();
    for (int i = base + t; i < endE; i += 1024) {
        int2 e = ebuf[i];
        int ld = e.y - d0;
        int p = lrow[ld] + atomicAdd(&lcnt[ld], 1);
        csrc[p] = e.x;
    }
}

// ---------------- aggregate32: PAIRED + split staging, outputs hi/lo fp16 ----
// Used for BOTH layer-0 (featA,el2A,b0 -> vhi0/vlo0) and layer-1
// (featB,el2B,b1 -> ahi/alo). The W-matvec lives in gemm_mfma1 now.
__global__ __launch_bounds__(256) void aggregate32(
    const int2* __restrict__ rowse, const int* __restrict__ csrc,
    const float2* __restrict__ el2, const float2* __restrict__ er2,
    const _Float16* __restrict__ feat16, const float* __restrict__ b,
    _Float16* __restrict__ ahi, _Float16* __restrict__ alo, int N) {
    __shared__ __attribute__((aligned(16))) int   stS0[4][64], stS1[4][64];
    __shared__ __attribute__((aligned(16))) float stX0[4][64], stY0[4][64];
    __shared__ __attribute__((aligned(16))) float stX1[4][64], stY1[4][64];
    int wave = threadIdx.x >> 6, lane = threadIdx.x & 63, h = lane >> 5;
    int g = rfl(blockIdx.x * 4 + wave);
    int n0 = 2 * g, n1 = n0 + 1;
    if (n0 >= N) return;
    bool has1 = (n1 < N);
    float bl = b[lane];
    int2 se0 = rowse[n0];
    int2 se1 = has1 ? rowse[n1] : make_int2(0, 0);
    int beg0 = rfl(se0.x), len0 = rfl(se0.y) - beg0;
    int beg1 = rfl(se1.x), len1 = rfl(se1.y) - beg1;
    float2 rr0 = er2[n0];
    float2 rr1 = has1 ? er2[n1] : make_float2(0.f, 0.f);
    const int*   stSw0 = stS0[wave];
    const int*   stSw1 = stS1[wave];
    const float* stWH0 = h ? stY0[wave] : stX0[wave];
    const float* stWH1 = h ? stY1[wave] : stX1[wave];
    float s0 = 0.f, acc0 = 0.f, s1 = 0.f, acc1 = 0.f;
    int chunks = max(len0, len1);
    for (int off = 0; off < chunks; off += 64) {
        bool a0 = off + lane < len0;
        bool a1 = off + lane < len1;
        int sv0 = a0 ? csrc[beg0 + off + lane] : 0;
        int sv1 = a1 ? csrc[beg1 + off + lane] : 0;
        stS0[wave][lane] = sv0;                  // early stores: index-only
        stS1[wave][lane] = sv1;
        float wx0 = 0.f, wy0 = 0.f, wx1 = 0.f, wy1 = 0.f;
        if (a0) {
            float2 l = el2[sv0];
            float t0 = l.x + rr0.x; t0 = t0 > 0.f ? t0 : NEG_SLOPE * t0;
            float t1 = l.y + rr0.y; t1 = t1 > 0.f ? t1 : NEG_SLOPE * t1;
            wx0 = __expf(t0); wy0 = __expf(t1);
        }
        if (a1) {
            float2 l = el2[sv1];
            float t0 = l.x + rr1.x; t0 = t0 > 0.f ? t0 : NEG_SLOPE * t0;
            float t1 = l.y + rr1.y; t1 = t1 > 0.f ? t1 : NEG_SLOPE * t1;
            wx1 = __expf(t0); wy1 = __expf(t1);
        }
        stX0[wave][lane] = wx0; stY0[wave][lane] = wy0;
        stX1[wave][lane] = wx1; stY1[wave][lane] = wy1;
        int cnt = (min(64, chunks - off) + 7) & ~7;
        for (int j = 0; j < cnt; j += 8) {
            int4 sA = *(const int4*)(stSw0 + j);
            int4 sB = *(const int4*)(stSw0 + j + 4);
            int4 tA = *(const int4*)(stSw1 + j);
            int4 tB = *(const int4*)(stSw1 + j + 4);
            float f0 = (float)feat16[(size_t)sA.x * 64 + lane];
            float f1 = (float)feat16[(size_t)sA.y * 64 + lane];
            float f2 = (float)feat16[(size_t)sA.z * 64 + lane];
            float f3 = (float)feat16[(size_t)sA.w * 64 + lane];
            float f4 = (float)feat16[(size_t)sB.x * 64 + lane];
            float f5 = (float)feat16[(size_t)sB.y * 64 + lane];
            float f6 = (float)feat16[(size_t)sB.z * 64 + lane];
            float f7 = (float)feat16[(size_t)sB.w * 64 + lane];
            float p0 = (float)feat16[(size_t)tA.x * 64 + lane];
            float p1 = (float)feat16[(size_t)tA.y * 64 + lane];
            float p2 = (float)feat16[(size_t)tA.z * 64 + lane];
            float p3 = (float)feat16[(size_t)tA.w * 64 + lane];
            float p4 = (float)feat16[(size_t)tB.x * 64 + lane];
            float p5 = (float)feat16[(size_t)tB.y * 64 + lane];
            float p6 = (float)feat16[(size_t)tB.z * 64 + lane];
            float p7 = (float)feat16[(size_t)tB.w * 64 + lane];
            float4 wv0 = *(const float4*)(stWH0 + j);
            float4 wv1 = *(const float4*)(stWH0 + j + 4);
            float4 xv0 = *(const float4*)(stWH1 + j);
            float4 xv1 = *(const float4*)(stWH1 + j + 4);
            s0 += ((wv0.x + wv0.y) + (wv0.z + wv0.w)) + ((wv1.x + wv1.y) + (wv1.z + wv1.w));
            acc0 = fmaf(wv0.x, f0, acc0);
            acc0 = fmaf(wv0.y, f1, acc0);
            acc0 = fmaf(wv0.z, f2, acc0);
            acc0 = fmaf(wv0.w, f3, acc0);
            acc0 = fmaf(wv1.x, f4, acc0);
            acc0 = fmaf(wv1.y, f5, acc0);
            acc0 = fmaf(wv1.z, f6, acc0);
            acc0 = fmaf(wv1.w, f7, acc0);
            s1 += ((xv0.x + xv0.y) + (xv0.z + xv0.w)) + ((xv1.x + xv1.y) + (xv1.z + xv1.w));
            acc1 = fmaf(xv0.x, p0, acc1);
            acc1 = fmaf(xv0.y, p1, acc1);
            acc1 = fmaf(xv0.z, p2, acc1);
            acc1 = fmaf(xv0.w, p3, acc1);
            acc1 = fmaf(xv1.x, p4, acc1);
            acc1 = fmaf(xv1.y, p5, acc1);
            acc1 = fmaf(xv1.z, p6, acc1);
            acc1 = fmaf(xv1.w, p7, acc1);
        }
    }
    float v = (s0 > 0.f) ? acc0 / s0 : 0.f;
    v = fmaxf(v + bl, 0.f);
    _Float16 hv = (_Float16)v;
    ahi[(size_t)n0 * 64 + lane] = hv;
    alo[(size_t)n0 * 64 + lane] = (_Float16)(v - (float)hv);
    if (has1) {
        float u = (s1 > 0.f) ? acc1 / s1 : 0.f;
        u = fmaxf(u + bl, 0.f);
        _Float16 hu = (_Float16)u;
        ahi[(size_t)n1 * 64 + lane] = hu;
        alo[(size_t)n1 * 64 + lane] = (_Float16)(u - (float)hu);
    }
}

// ---------------- gemm_mfma1: MFMA 64->64 hi/lo + layer-1 logits ----
// Replaces the fp32 matvec that used to live inside agg0_gemm1.
__global__ __launch_bounds__(256) void gemm_mfma1(
    const _Float16* __restrict__ Ahi, const _Float16* __restrict__ Alo,
    const _Float16* __restrict__ Wp,
    const float* __restrict__ AL, const float* __restrict__ AR,
    _Float16* __restrict__ featB, float2* __restrict__ el2, float2* __restrict__ er2,
    int N) {
    constexpr int KC = 2, NT = 4;
    int wave = threadIdx.x >> 6, lane = threadIdx.x & 63;
    int mtile = blockIdx.x * 4 + wave;
    if (mtile * 16 >= N) return;
    int m0 = mtile * 16;
    int c = lane & 15, q = lane >> 4;
    v4f acc[NT];
#pragma unroll
    for (int t = 0; t < NT; t++) acc[t] = (v4f){0.f, 0.f, 0.f, 0.f};
    const size_t arow = (size_t)(m0 + c) * 64 + q * 8;
#pragma unroll
    for (int kc = 0; kc < KC; kc++) {
        half8 ah = *(const half8*)(Ahi + arow + kc * 32);
        half8 av = *(const half8*)(Alo + arow + kc * 32);
#pragma unroll
        for (int t = 0; t < NT; t++) {
            half8 b = *(const half8*)(Wp + ((size_t)(t * KC + kc) * 64 + lane) * 8);
            acc[t] = __builtin_amdgcn_mfma_f32_16x16x32_f16(ah, b, acc[t], 0, 0, 0);
            acc[t] = __builtin_amdgcn_mfma_f32_16x16x32_f16(av, b, acc[t], 0, 0, 0);
        }
    }
#pragma unroll
    for (int t = 0; t < NT; t++)
#pragma unroll
        for (int r = 0; r < 4; r++) {
            int row = m0 + q * 4 + r;
            featB[(size_t)row * 64 + t * 16 + c] = (_Float16)acc[t][r];
        }
    float alv[NT], arv[NT];
#pragma unroll
    for (int t = 0; t < NT; t++) { alv[t] = AL[t * 16 + c]; arv[t] = AR[t * 16 + c]; }
#pragma unroll
    for (int r = 0; r < 4; r++) {
        float l0 = 0.f, l1 = 0.f, r0 = 0.f, r1 = 0.f;
#pragma unroll
        for (int t = 0; t < NT; t++) {
            float v = acc[t][r];
            if (t < 2) { l0 = fmaf(v, alv[t], l0); r0 = fmaf(v, arv[t], r0); }
            else       { l1 = fmaf(v, alv[t], l1); r1 = fmaf(v, arv[t], r1); }
        }
#pragma unroll
        for (int m = 1; m < 16; m <<= 1) {
            l0 += __shfl_xor(l0, m, 64);
            l1 += __shfl_xor(l1, m, 64);
            r0 += __shfl_xor(r0, m, 64);
            r1 += __shfl_xor(r1, m, 64);
        }
        if (c == 0) {
            int row = m0 + q * 4 + r;
            el2[row] = make_float2(l0, l1);
            er2[row] = make_float2(r0, r1);
        }
    }
}

// ---------------- gemm2: MFMA 64->128, half2-interleaved feat + layer-2 logits ----
__global__ __launch_bounds__(256) void gemm_mfma2(
    const _Float16* __restrict__ Ahi, const _Float16* __restrict__ Alo,
    const _Float16* __restrict__ Wp,
    const float* __restrict__ AL, const float* __restrict__ AR,
    __half2* __restrict__ feat2, float2* __restrict__ el2, float2* __restrict__ er2,
    int N) {
    constexpr int KC = 2, NT = 8;
    int wave = threadIdx.x >> 6, lane = threadIdx.x & 63;
    int mtile = blockIdx.x * 4 + wave;
    if (mtile * 16 >= N) return;
    int m0 = mtile * 16;
    int c = lane & 15, q = lane >> 4;
    v4f acc[NT];
#pragma unroll
    for (int t = 0; t < NT; t++) acc[t] = (v4f){0.f, 0.f, 0.f, 0.f};
    const size_t arow = (size_t)(m0 + c) * 64 + q * 8;
#pragma unroll
    for (int kc = 0; kc < KC; kc++) {
        half8 ah = *(const half8*)(Ahi + arow + kc * 32);
        half8 av = *(const half8*)(Alo + arow + kc * 32);
#pragma unroll
        for (int t = 0; t < NT; t++) {
            half8 b = *(const half8*)(Wp + ((size_t)(t * KC + kc) * 64 + lane) * 8);
            acc[t] = __builtin_amdgcn_mfma_f32_16x16x32_f16(ah, b, acc[t], 0, 0, 0);
            acc[t] = __builtin_amdgcn_mfma_f32_16x16x32_f16(av, b, acc[t], 0, 0, 0);
        }
    }
#pragma unroll
    for (int t = 0; t < NT / 2; t++)
#pragma unroll
        for (int r = 0; r < 4; r++) {
            int row = m0 + q * 4 + r;
            feat2[(size_t)row * 64 + t * 16 + c] =
                __floats2half2_rn(acc[t][r], acc[t + NT / 2][r]);
        }
    float alv[NT], arv[NT];
#pragma unroll
    for (int t = 0; t < NT; t++) { alv[t] = AL[t * 16 + c]; arv[t] = AR[t * 16 + c]; }
#pragma unroll
    for (int r = 0; r < 4; r++) {
        float l0 = 0.f, l1 = 0.f, r0 = 0.f, r1 = 0.f;
#pragma unroll
        for (int t = 0; t < NT; t++) {
            float v = acc[t][r];
            if (t < NT / 2) { l0 = fmaf(v, alv[t], l0); r0 = fmaf(v, arv[t], r0); }
            else            { l1 = fmaf(v, alv[t], l1); r1 = fmaf(v, arv[t], r1); }
        }
#pragma unroll
        for (int m = 1; m < 16; m <<= 1) {
            l0 += __shfl_xor(l0, m, 64);
            l1 += __shfl_xor(l1, m, 64);
            r0 += __shfl_xor(r0, m, 64);
            r1 += __shfl_xor(r1, m, 64);
        }
        if (c == 0) {
            int row = m0 + q * 4 + r;
            el2[row] = make_float2(l0, l1);
            er2[row] = make_float2(r0, r1);
        }
    }
}

// ---------------- agg2 PAIRED + split staging; mean over heads ----------------
__global__ __launch_bounds__(256) void aggregate64_mean(
    const int2* __restrict__ rowse, const int* __restrict__ csrc,
    const float2* __restrict__ el2, const float2* __restrict__ er2,
    const __half2* __restrict__ feat2, const float* __restrict__ b,
    float* __restrict__ out, int N) {
    __shared__ __attribute__((aligned(16))) int   stS0[4][64], stS1[4][64];
    __shared__ __attribute__((aligned(16))) float stX0[4][64], stY0[4][64];
    __shared__ __attribute__((aligned(16))) float stX1[4][64], stY1[4][64];
    int wave = threadIdx.x >> 6, lane = threadIdx.x & 63;
    int g = rfl(blockIdx.x * 4 + wave);
    int n0 = 2 * g, n1 = n0 + 1;
    if (n0 >= N) return;
    bool has1 = (n1 < N);
    float b0v = b[lane], b1v = b[64 + lane];
    int2 se0 = rowse[n0];
    int2 se1 = has1 ? rowse[n1] : make_int2(0, 0);
    int beg0 = rfl(se0.x), len0 = rfl(se0.y) - beg0;
    int beg1 = rfl(se1.x), len1 = rfl(se1.y) - beg1;
    float2 rr0 = er2[n0];
    float2 rr1 = has1 ? er2[n1] : make_float2(0.f, 0.f);
    const int* stSw0 = stS0[wave];
    const int* stSw1 = stS1[wave];
    float s00 = 0.f, s01 = 0.f, a00 = 0.f, a01 = 0.f;
    float s10 = 0.f, s11 = 0.f, a10 = 0.f, a11 = 0.f;
    int chunks = max(len0, len1);
    for (int off = 0; off < chunks; off += 64) {
        bool a0 = off + lane < len0;
        bool a1 = off + lane < len1;
        int sv0 = a0 ? csrc[beg0 + off + lane] : 0;
        int sv1 = a1 ? csrc[beg1 + off + lane] : 0;
        stS0[wave][lane] = sv0;
        stS1[wave][lane] = sv1;
        float wx0 = 0.f, wy0 = 0.f, wx1 = 0.f, wy1 = 0.f;
        if (a0) {
            float2 l = el2[sv0];
            float t0 = l.x + rr0.x; t0 = t0 > 0.f ? t0 : NEG_SLOPE * t0;
            float t1 = l.y + rr0.y; t1 = t1 > 0.f ? t1 : NEG_SLOPE * t1;
            wx0 = __expf(t0); wy0 = __expf(t1);
        }
        if (a1) {
            float2 l = el2[sv1];
            float t0 = l.x + rr1.x; t0 = t0 > 0.f ? t0 : NEG_SLOPE * t0;
            float t1 = l.y + rr1.y; t1 = t1 > 0.f ? t1 : NEG_SLOPE * t1;
            wx1 = __expf(t0); wy1 = __expf(t1);
        }
        stX0[wave][lane] = wx0; stY0[wave][lane] = wy0;
        stX1[wave][lane] = wx1; stY1[wave][lane] = wy1;
        int cnt = (min(64, chunks - off) + 7) & ~7;
        for (int j = 0; j < cnt; j += 8) {
            int4 sA = *(const int4*)(stSw0 + j);
            int4 sB = *(const int4*)(stSw0 + j + 4);
            int4 tA = *(const int4*)(stSw1 + j);
            int4 tB = *(const int4*)(stSw1 + j + 4);
            float2 fv0[8], fv1[8];
            fv0[0] = __half22float2(feat2[(size_t)sA.x * 64 + lane]);
            fv0[1] = __half22float2(feat2[(size_t)sA.y * 64 + lane]);
            fv0[2] = __half22float2(feat2[(size_t)sA.z * 64 + lane]);
            fv0[3] = __half22float2(feat2[(size_t)sA.w * 64 + lane]);
            fv0[4] = __half22float2(feat2[(size_t)sB.x * 64 + lane]);
            fv0[5] = __half22float2(feat2[(size_t)sB.y * 64 + lane]);
            fv0[6] = __half22float2(feat2[(size_t)sB.z * 64 + lane]);
            fv0[7] = __half22float2(feat2[(size_t)sB.w * 64 + lane]);
            fv1[0] = __half22float2(feat2[(size_t)tA.x * 64 + lane]);
            fv1[1] = __half22float2(feat2[(size_t)tA.y * 64 + lane]);
            fv1[2] = __half22float2(feat2[(size_t)tA.z * 64 + lane]);
            fv1[3] = __half22float2(feat2[(size_t)tA.w * 64 + lane]);
            fv1[4] = __half22float2(feat2[(size_t)tB.x * 64 + lane]);
            fv1[5] = __half22float2(feat2[(size_t)tB.y * 64 + lane]);
            fv1[6] = __half22float2(feat2[(size_t)tB.z * 64 + lane]);
            fv1[7] = __half22float2(feat2[(size_t)tB.w * 64 + lane]);
            float4 wx0v = *(const float4*)(stX0[wave] + j);
            float4 wx0w = *(const float4*)(stX0[wave] + j + 4);
            float4 wy0v = *(const float4*)(stY0[wave] + j);
            float4 wy0w = *(const float4*)(stY0[wave] + j + 4);
            float4 wx1v = *(const float4*)(stX1[wave] + j);
            float4 wx1w = *(const float4*)(stX1[wave] + j + 4);
            float4 wy1v = *(const float4*)(stY1[wave] + j);
            float4 wy1w = *(const float4*)(stY1[wave] + j + 4);
            float wxs0[8] = {wx0v.x, wx0v.y, wx0v.z, wx0v.w, wx0w.x, wx0w.y, wx0w.z, wx0w.w};
            float wys0[8] = {wy0v.x, wy0v.y, wy0v.z, wy0v.w, wy0w.x, wy0w.y, wy0w.z, wy0w.w};
            float wxs1[8] = {wx1v.x, wx1v.y, wx1v.z, wx1v.w, wx1w.x, wx1w.y, wx1w.z, wx1w.w};
            float wys1[8] = {wy1v.x, wy1v.y, wy1v.z, wy1v.w, wy1w.x, wy1w.y, wy1w.z, wy1w.w};
#pragma unroll
            for (int u = 0; u < 8; u++) {
                s00 += wxs0[u]; s01 += wys0[u];
                a00 = fmaf(wxs0[u], fv0[u].x, a00);
                a01 = fmaf(wys0[u], fv0[u].y, a01);
            }
#pragma unroll
            for (int u = 0; u < 8; u++) {
                s10 += wxs1[u]; s11 += wys1[u];
                a10 = fmaf(wxs1[u], fv1[u].x, a10);
                a11 = fmaf(wys1[u], fv1[u].y, a11);
            }
        }
    }
    float v0 = (s00 > 0.f) ? a00 / s00 : 0.f;
    float v1 = (s01 > 0.f) ? a01 / s01 : 0.f;
    out[(size_t)n0 * 64 + lane] = 0.5f * ((v0 + b0v) + (v1 + b1v));
    if (has1) {
        float u0 = (s10 > 0.f) ? a10 / s10 : 0.f;
        float u1 = (s11 > 0.f) ? a11 / s11 : 0.f;
        out[(size_t)n1 * 64 + lane] = 0.5f * ((u0 + b0v) + (u1 + b1v));
    }
}

// ---------------- launcher ----------------

extern "C" void kernel_launch(void* const* d_in, const int* in_sizes, int n_in,
                              void* d_out, int out_size, void* d_ws, size_t ws_size,
                              hipStream_t stream) {
    const float* x   = (const float*)d_in[0];
    const int*   src = (const int*)d_in[1];
    const int*   dst = (const int*)d_in[2];
    const float* W0  = (const float*)d_in[3];
    const float* al0 = (const float*)d_in[4];
    const float* ar0 = (const float*)d_in[5];
    const float* b0  = (const float*)d_in[6];
    const float* W1  = (const float*)d_in[7];
    const float* al1 = (const float*)d_in[8];
    const float* ar1 = (const float*)d_in[9];
    const float* b1  = (const float*)d_in[10];
    const float* W2  = (const float*)d_in[11];
    const float* al2 = (const float*)d_in[12];
    const float* ar2 = (const float*)d_in[13];
    const float* b2  = (const float*)d_in[14];
    float* out = (float*)d_out;

    const int N = NNODES;
    const int E = in_sizes[1];

    char* p = (char*)d_ws;
    auto alloc = [&](size_t bytes) {
        void* r = (void*)p;
        p += (bytes + 255) & ~(size_t)255;
        return r;
    };
    int*    bcursor = (int*)alloc((size_t)NBKT * 16 * 4);
    int2*   rowse   = (int2*)alloc((size_t)N * 8);
    int2*   ebuf    = (int2*)alloc(((size_t)NBKT * STRIDE + 4096) * 8);
    int*    csrc    = (int*)alloc(((size_t)NBKT * STRIDE + 4096) * 4);
    float2* el2A    = (float2*)alloc((size_t)N * 8);
    float2* er2A    = (float2*)alloc((size_t)N * 8);
    float2* el2B    = (float2*)alloc((size_t)N * 8);
    float2* er2B    = (float2*)alloc((size_t)N * 8);
    _Float16* ahi   = (_Float16*)alloc((size_t)N * 64 * 2);
    _Float16* alo   = (_Float16*)alloc((size_t)N * 64 * 2);
    _Float16* vhi0  = (_Float16*)alloc((size_t)N * 64 * 2);
    _Float16* vlo0  = (_Float16*)alloc((size_t)N * 64 * 2);
    void*   featA   = alloc((size_t)N * 64 * 4);
    _Float16* featB = (_Float16*)alloc((size_t)N * 64 * 2);
    _Float16* Wp2   = (_Float16*)alloc(8 * 2 * 64 * 8 * 2);
    _Float16* Wp1   = (_Float16*)alloc(4 * 2 * 64 * 8 * 2);

    // 0) zero bucket counters (partition counts from zero)
    hipMemsetAsync(bcursor, 0, (size_t)NBKT * 16 * 4, stream);
    // 1) gemm0 + pack W2 + pack W1 + partition, one launch (independent jobs overlap)
    int nch = (E + PCHUNK - 1) / PCHUNK;
    kernelAB<<<788 + nch, 256, 0, stream>>>(x, W0, al0, ar0, (_Float16*)featA, el2A, er2A,
                                            W2, Wp2, W1, Wp1, src, dst, bcursor, ebuf, E, N);
    // 2) local sort -> rowse + csrc (1024 threads/bucket)
    local_sort<<<NBKT, 1024, 0, stream>>>(ebuf, bcursor, rowse, csrc, N);

    int npair = (N + 1) / 2;
    int nbp = (npair + 3) / 4;
    int gb = (N / 16 + 3) / 4;
    // 3) layer-0 aggregate (PAIRED, split-stage) -> hi/lo fp16
    aggregate32<<<nbp, 256, 0, stream>>>(rowse, csrc, el2A, er2A, (const _Float16*)featA,
                                         b0, vhi0, vlo0, N);
    // 4) gemm1 MFMA (64->64) + layer-1 logits
    gemm_mfma1<<<gb, 256, 0, stream>>>(vhi0, vlo0, Wp1, al1, ar1, featB, el2B, er2B, N);
    // 5) layer-1 aggregate (PAIRED, split-stage) -> hi/lo fp16
    aggregate32<<<nbp, 256, 0, stream>>>(rowse, csrc, el2B, er2B, featB, b1, ahi, alo, N);
    // 6) gemm2 MFMA (64->128) + layer-2 logits
    gemm_mfma2<<<gb, 256, 0, stream>>>(ahi, alo, Wp2, al2, ar2, (__half2*)featA, el2A, er2A, N);
    // 7) layer-2 aggregate (PAIRED, split-stage), mean over heads
    aggregate64_mean<<<nbp, 256, 0, stream>>>(rowse, csrc, el2A, er2A, (const __half2*)featA,
                                              b2, out, N);
}

// Round 8
// 211.801 us; speedup vs baseline: 1.0886x; 1.0064x over previous
//
#include <hip/hip_runtime.h>
#include <hip/hip_bf16.h>
#include <hip/hip_fp16.h>

#define NNODES 50000
#define NEG_SLOPE 0.2f
#define BKT_SHIFT 8
#define NBKT ((NNODES + 255) >> 8)   // 196 buckets of 256 dsts
#define STRIDE 5120                   // fixed slots per bucket (avg 4082, +16 sigma)
#define PCHUNK 2048                   // partition chunk (256 thr x 8 edges)
#define PEPT 8

typedef _Float16 half8 __attribute__((ext_vector_type(8)));
typedef float v4f __attribute__((ext_vector_type(4)));

__device__ __forceinline__ int rfl(int v) { return __builtin_amdgcn_readfirstlane(v); }

// pack W[K][C] fp32 into MFMA B-fragment order
__device__ __forceinline__ void pack_one(const float* W, _Float16* Wp, int K, int C, int tid) {
    int KC = K / 32;
    int l = tid & 63;
    int kc = (tid >> 6) % KC;
    int t = tid / (KC * 64);
    int cc = l & 15, q = l >> 4;
    half8 b;
#pragma unroll
    for (int j = 0; j < 8; j++)
        b[j] = (_Float16)W[(size_t)(kc * 32 + q * 8 + j) * C + t * 16 + cc];
    *(half8*)(Wp + (size_t)tid * 8) = b;
}

// ---------------- Kernel AB: gemm0 + pack W2 + pack W1 + edge partition ----------
// blocks [0,782): gemm0 (W0 packed to LDS per block) | [782,786): pack W2
// | [786,788): pack W1 | rest: partition
__global__ __launch_bounds__(256) void kernelAB(
    const float* __restrict__ x, const float* __restrict__ W0,
    const float* __restrict__ AL, const float* __restrict__ AR,
    _Float16* __restrict__ featA, float2* __restrict__ el2A, float2* __restrict__ er2A,
    const float* __restrict__ W2, _Float16* __restrict__ Wp2,
    const float* __restrict__ W1, _Float16* __restrict__ Wp1,
    const int* __restrict__ src, const int* __restrict__ dst,
    int* __restrict__ bcursor, int2* __restrict__ ebuf, int E, int N) {
    int blk = blockIdx.x;
    if (blk >= 788) {
        // ---- partition branch ----
        __shared__ int hist[NBKT];
        __shared__ int gbase[NBKT];
        int t = threadIdx.x;
        for (int i = t; i < NBKT; i += 256) hist[i] = 0;
        __syncthreads();
        int base = (blk - 788) * PCHUNK;
        int sreg[PEPT], dreg[PEPT], rreg[PEPT], breg[PEPT];
#pragma unroll
        for (int k = 0; k < PEPT; k++) {
            int i = base + k * 256 + t;
            if (i < E) {
                sreg[k] = src[i];
                dreg[k] = dst[i];
                breg[k] = dreg[k] >> BKT_SHIFT;
                rreg[k] = atomicAdd(&hist[breg[k]], 1);
            } else {
                breg[k] = -1;
            }
        }
        __syncthreads();
        for (int i = t; i < NBKT; i += 256)
            if (hist[i]) gbase[i] = i * STRIDE + atomicAdd(&bcursor[i * 16], hist[i]);
        __syncthreads();
#pragma unroll
        for (int k = 0; k < PEPT; k++) {
            if (breg[k] >= 0)
                ebuf[(size_t)(gbase[breg[k]] + rreg[k])] = make_int2(sreg[k], dreg[k]);
        }
        return;
    }
    if (blk >= 786) {
        // pack W1 (64 -> 64): KC=2, 4 col-tiles -> 512 tids
        int tid = (blk - 786) * 256 + threadIdx.x;
        if (tid < 4 * 2 * 64) pack_one(W1, Wp1, 64, 64, tid);
        return;
    }
    if (blk >= 782) {
        int tid = (blk - 782) * 256 + threadIdx.x;
        if (tid < 8 * 2 * 64) pack_one(W2, Wp2, 64, 128, tid);
        return;
    }
    // ---- gemm0 branch: x fp32 hi/lo split, W0 packed to LDS once per block ----
    __shared__ _Float16 w0p[16 * 64 * 8];   // 16 KB: fragment (t*4+kc)*64+lane
    for (int i = threadIdx.x; i < 1024; i += 256) {
        int l = i & 63, kc = (i >> 6) & 3, t = i >> 8;
        int cc = l & 15, q = l >> 4;
        half8 b;
#pragma unroll
        for (int j = 0; j < 8; j++)
            b[j] = (_Float16)W0[(size_t)(kc * 32 + q * 8 + j) * 64 + t * 16 + cc];
        *(half8*)(w0p + (size_t)i * 8) = b;
    }
    __syncthreads();                         // ALL waves reach this before any exits
    int wave = threadIdx.x >> 6, lane = threadIdx.x & 63;
    int mtile = blk * 4 + wave;
    if (mtile * 16 >= N) return;
    int m0 = mtile * 16;
    int c = lane & 15, q = lane >> 4;
    v4f acc[4];
#pragma unroll
    for (int t = 0; t < 4; t++) acc[t] = (v4f){0.f, 0.f, 0.f, 0.f};
    const size_t arow = (size_t)(m0 + c) * 128 + q * 8;
#pragma unroll
    for (int kc = 0; kc < 4; kc++) {
        const float* xr = x + arow + kc * 32;
        float4 f0 = *(const float4*)xr;
        float4 f1 = *(const float4*)(xr + 4);
        float fv[8] = {f0.x, f0.y, f0.z, f0.w, f1.x, f1.y, f1.z, f1.w};
        half8 ah, av;
#pragma unroll
        for (int j = 0; j < 8; j++) {
            ah[j] = (_Float16)fv[j];
            av[j] = (_Float16)(fv[j] - (float)ah[j]);
        }
#pragma unroll
        for (int tt = 0; tt < 4; tt++) {
            half8 b = *(const half8*)(w0p + ((size_t)(tt * 4 + kc) * 64 + lane) * 8);
            acc[tt] = __builtin_amdgcn_mfma_f32_16x16x32_f16(ah, b, acc[tt], 0, 0, 0);
            acc[tt] = __builtin_amdgcn_mfma_f32_16x16x32_f16(av, b, acc[tt], 0, 0, 0);
        }
    }
#pragma unroll
    for (int tt = 0; tt < 4; tt++)
#pragma unroll
        for (int r = 0; r < 4; r++) {
            int row = m0 + q * 4 + r;
            featA[(size_t)row * 64 + tt * 16 + c] = (_Float16)acc[tt][r];
        }
    float alv[4], arv[4];
#pragma unroll
    for (int tt = 0; tt < 4; tt++) { alv[tt] = AL[tt * 16 + c]; arv[tt] = AR[tt * 16 + c]; }
#pragma unroll
    for (int r = 0; r < 4; r++) {
        float l0 = 0.f, l1 = 0.f, r0 = 0.f, r1 = 0.f;
#pragma unroll
        for (int tt = 0; tt < 4; tt++) {
            float v = acc[tt][r];
            if (tt < 2) { l0 = fmaf(v, alv[tt], l0); r0 = fmaf(v, arv[tt], r0); }
            else        { l1 = fmaf(v, alv[tt], l1); r1 = fmaf(v, arv[tt], r1); }
        }
#pragma unroll
        for (int m = 1; m < 16; m <<= 1) {
            l0 += __shfl_xor(l0, m, 64);
            l1 += __shfl_xor(l1, m, 64);
            r0 += __shfl_xor(r0, m, 64);
            r1 += __shfl_xor(r1, m, 64);
        }
        if (c == 0) {
            int row = m0 + q * 4 + r;
            el2A[row] = make_float2(l0, l1);
            er2A[row] = make_float2(r0, r1);
        }
    }
}

// ---------------- local sort: 1024 threads/bucket ----
__global__ __launch_bounds__(1024) void local_sort(const int2* __restrict__ ebuf,
                                                   const int* __restrict__ bcursor,
                                                   int2* __restrict__ rowse,
                                                   int* __restrict__ csrc, int N) {
    __shared__ int lcnt[256], lrow[256], ws[4];
    int b = blockIdx.x;
    int d0 = b << BKT_SHIFT;
    int t = threadIdx.x;
    int base = b * STRIDE;
    int endE = base + bcursor[b * 16];
    if (t < 256) lcnt[t] = 0;
    __syncthreads();
    for (int i = base + t; i < endE; i += 1024)
        atomicAdd(&lcnt[ebuf[i].y - d0], 1);
    __syncthreads();
    int v = (t < 256) ? lcnt[t] : 0;
    int lane = t & 63;
    int x = v;
#pragma unroll
    for (int m = 1; m < 64; m <<= 1) {
        int y = __shfl_up(x, m, 64);
        if (lane >= m) x += y;
    }
    if (t < 256 && lane == 63) ws[t >> 6] = x;
    __syncthreads();
    if (t < 256) {
        int w = t >> 6, waveoff = 0;
#pragma unroll
        for (int k = 0; k < 4; k++) if (k < w) waveoff += ws[k];
        int excl = base + waveoff + x - v;
        lrow[t] = excl;
        int d = d0 + t;
        if (d < N) rowse[d] = make_int2(excl, excl + v);
        lcnt[t] = 0;
    }
    __syncthreads();
    for (int i = base + t; i < endE; i += 1024) {
        int2 e = ebuf[i];
        int ld = e.y - d0;
        int p = lrow[ld] + atomicAdd(&lcnt[ld], 1);
        csrc[p] = e.x;
    }
}

// ---------------- aggregate32: PAIRED + split staging, outputs hi/lo fp16 ----
__global__ __launch_bounds__(256) void aggregate32(
    const int2* __restrict__ rowse, const int* __restrict__ csrc,
    const float2* __restrict__ el2, const float2* __restrict__ er2,
    const _Float16* __restrict__ feat16, const float* __restrict__ b,
    _Float16* __restrict__ ahi, _Float16* __restrict__ alo, int N) {
    __shared__ __attribute__((aligned(16))) int   stS0[4][64], stS1[4][64];
    __shared__ __attribute__((aligned(16))) float stX0[4][64], stY0[4][64];
    __shared__ __attribute__((aligned(16))) float stX1[4][64], stY1[4][64];
    int wave = threadIdx.x >> 6, lane = threadIdx.x & 63, h = lane >> 5;
    int g = rfl(blockIdx.x * 4 + wave);
    int n0 = 2 * g, n1 = n0 + 1;
    if (n0 >= N) return;
    bool has1 = (n1 < N);
    float bl = b[lane];
    int2 se0 = rowse[n0];
    int2 se1 = has1 ? rowse[n1] : make_int2(0, 0);
    int beg0 = rfl(se0.x), len0 = rfl(se0.y) - beg0;
    int beg1 = rfl(se1.x), len1 = rfl(se1.y) - beg1;
    float2 rr0 = er2[n0];
    float2 rr1 = has1 ? er2[n1] : make_float2(0.f, 0.f);
    const int*   stSw0 = stS0[wave];
    const int*   stSw1 = stS1[wave];
    const float* stWH0 = h ? stY0[wave] : stX0[wave];
    const float* stWH1 = h ? stY1[wave] : stX1[wave];
    float s0 = 0.f, acc0 = 0.f, s1 = 0.f, acc1 = 0.f;
    int chunks = max(len0, len1);
    for (int off = 0; off < chunks; off += 64) {
        bool a0 = off + lane < len0;
        bool a1 = off + lane < len1;
        int sv0 = a0 ? csrc[beg0 + off + lane] : 0;
        int sv1 = a1 ? csrc[beg1 + off + lane] : 0;
        stS0[wave][lane] = sv0;                  // early stores: index-only
        stS1[wave][lane] = sv1;
        float wx0 = 0.f, wy0 = 0.f, wx1 = 0.f, wy1 = 0.f;
        if (a0) {
            float2 l = el2[sv0];
            float t0 = l.x + rr0.x; t0 = t0 > 0.f ? t0 : NEG_SLOPE * t0;
            float t1 = l.y + rr0.y; t1 = t1 > 0.f ? t1 : NEG_SLOPE * t1;
            wx0 = __expf(t0); wy0 = __expf(t1);
        }
        if (a1) {
            float2 l = el2[sv1];
            float t0 = l.x + rr1.x; t0 = t0 > 0.f ? t0 : NEG_SLOPE * t0;
            float t1 = l.y + rr1.y; t1 = t1 > 0.f ? t1 : NEG_SLOPE * t1;
            wx1 = __expf(t0); wy1 = __expf(t1);
        }
        stX0[wave][lane] = wx0; stY0[wave][lane] = wy0;
        stX1[wave][lane] = wx1; stY1[wave][lane] = wy1;
        int cnt = (min(64, chunks - off) + 7) & ~7;
        for (int j = 0; j < cnt; j += 8) {
            int4 sA = *(const int4*)(stSw0 + j);
            int4 sB = *(const int4*)(stSw0 + j + 4);
            int4 tA = *(const int4*)(stSw1 + j);
            int4 tB = *(const int4*)(stSw1 + j + 4);
            float f0 = (float)feat16[(size_t)sA.x * 64 + lane];
            float f1 = (float)feat16[(size_t)sA.y * 64 + lane];
            float f2 = (float)feat16[(size_t)sA.z * 64 + lane];
            float f3 = (float)feat16[(size_t)sA.w * 64 + lane];
            float f4 = (float)feat16[(size_t)sB.x * 64 + lane];
            float f5 = (float)feat16[(size_t)sB.y * 64 + lane];
            float f6 = (float)feat16[(size_t)sB.z * 64 + lane];
            float f7 = (float)feat16[(size_t)sB.w * 64 + lane];
            float p0 = (float)feat16[(size_t)tA.x * 64 + lane];
            float p1 = (float)feat16[(size_t)tA.y * 64 + lane];
            float p2 = (float)feat16[(size_t)tA.z * 64 + lane];
            float p3 = (float)feat16[(size_t)tA.w * 64 + lane];
            float p4 = (float)feat16[(size_t)tB.x * 64 + lane];
            float p5 = (float)feat16[(size_t)tB.y * 64 + lane];
            float p6 = (float)feat16[(size_t)tB.z * 64 + lane];
            float p7 = (float)feat16[(size_t)tB.w * 64 + lane];
            float4 wv0 = *(const float4*)(stWH0 + j);
            float4 wv1 = *(const float4*)(stWH0 + j + 4);
            float4 xv0 = *(const float4*)(stWH1 + j);
            float4 xv1 = *(const float4*)(stWH1 + j + 4);
            s0 += ((wv0.x + wv0.y) + (wv0.z + wv0.w)) + ((wv1.x + wv1.y) + (wv1.z + wv1.w));
            acc0 = fmaf(wv0.x, f0, acc0);
            acc0 = fmaf(wv0.y, f1, acc0);
            acc0 = fmaf(wv0.z, f2, acc0);
            acc0 = fmaf(wv0.w, f3, acc0);
            acc0 = fmaf(wv1.x, f4, acc0);
            acc0 = fmaf(wv1.y, f5, acc0);
            acc0 = fmaf(wv1.z, f6, acc0);
            acc0 = fmaf(wv1.w, f7, acc0);
            s1 += ((xv0.x + xv0.y) + (xv0.z + xv0.w)) + ((xv1.x + xv1.y) + (xv1.z + xv1.w));
            acc1 = fmaf(xv0.x, p0, acc1);
            acc1 = fmaf(xv0.y, p1, acc1);
            acc1 = fmaf(xv0.z, p2, acc1);
            acc1 = fmaf(xv0.w, p3, acc1);
            acc1 = fmaf(xv1.x, p4, acc1);
            acc1 = fmaf(xv1.y, p5, acc1);
            acc1 = fmaf(xv1.z, p6, acc1);
            acc1 = fmaf(xv1.w, p7, acc1);
        }
    }
    float v = (s0 > 0.f) ? acc0 / s0 : 0.f;
    v = fmaxf(v + bl, 0.f);
    _Float16 hv = (_Float16)v;
    ahi[(size_t)n0 * 64 + lane] = hv;
    alo[(size_t)n0 * 64 + lane] = (_Float16)(v - (float)hv);
    if (has1) {
        float u = (s1 > 0.f) ? acc1 / s1 : 0.f;
        u = fmaxf(u + bl, 0.f);
        _Float16 hu = (_Float16)u;
        ahi[(size_t)n1 * 64 + lane] = hu;
        alo[(size_t)n1 * 64 + lane] = (_Float16)(u - (float)hu);
    }
}

// ---------------- gemm_mfma1: MFMA 64->64 hi/lo + layer-1 logits ----
__global__ __launch_bounds__(256) void gemm_mfma1(
    const _Float16* __restrict__ Ahi, const _Float16* __restrict__ Alo,
    const _Float16* __restrict__ Wp,
    const float* __restrict__ AL, const float* __restrict__ AR,
    _Float16* __restrict__ featB, float2* __restrict__ el2, float2* __restrict__ er2,
    int N) {
    constexpr int KC = 2, NT = 4;
    int wave = threadIdx.x >> 6, lane = threadIdx.x & 63;
    int mtile = blockIdx.x * 4 + wave;
    if (mtile * 16 >= N) return;
    int m0 = mtile * 16;
    int c = lane & 15, q = lane >> 4;
    v4f acc[NT];
#pragma unroll
    for (int t = 0; t < NT; t++) acc[t] = (v4f){0.f, 0.f, 0.f, 0.f};
    const size_t arow = (size_t)(m0 + c) * 64 + q * 8;
#pragma unroll
    for (int kc = 0; kc < KC; kc++) {
        half8 ah = *(const half8*)(Ahi + arow + kc * 32);
        half8 av = *(const half8*)(Alo + arow + kc * 32);
#pragma unroll
        for (int t = 0; t < NT; t++) {
            half8 b = *(const half8*)(Wp + ((size_t)(t * KC + kc) * 64 + lane) * 8);
            acc[t] = __builtin_amdgcn_mfma_f32_16x16x32_f16(ah, b, acc[t], 0, 0, 0);
            acc[t] = __builtin_amdgcn_mfma_f32_16x16x32_f16(av, b, acc[t], 0, 0, 0);
        }
    }
#pragma unroll
    for (int t = 0; t < NT; t++)
#pragma unroll
        for (int r = 0; r < 4; r++) {
            int row = m0 + q * 4 + r;
            featB[(size_t)row * 64 + t * 16 + c] = (_Float16)acc[t][r];
        }
    float alv[NT], arv[NT];
#pragma unroll
    for (int t = 0; t < NT; t++) { alv[t] = AL[t * 16 + c]; arv[t] = AR[t * 16 + c]; }
#pragma unroll
    for (int r = 0; r < 4; r++) {
        float l0 = 0.f, l1 = 0.f, r0 = 0.f, r1 = 0.f;
#pragma unroll
        for (int t = 0; t < NT; t++) {
            float v = acc[t][r];
            if (t < 2) { l0 = fmaf(v, alv[t], l0); r0 = fmaf(v, arv[t], r0); }
            else       { l1 = fmaf(v, alv[t], l1); r1 = fmaf(v, arv[t], r1); }
        }
#pragma unroll
        for (int m = 1; m < 16; m <<= 1) {
            l0 += __shfl_xor(l0, m, 64);
            l1 += __shfl_xor(l1, m, 64);
            r0 += __shfl_xor(r0, m, 64);
            r1 += __shfl_xor(r1, m, 64);
        }
        if (c == 0) {
            int row = m0 + q * 4 + r;
            el2[row] = make_float2(l0, l1);
            er2[row] = make_float2(r0, r1);
        }
    }
}

// ---------------- gemm2: MFMA 64->128, half2-interleaved feat + layer-2 logits ----
__global__ __launch_bounds__(256) void gemm_mfma2(
    const _Float16* __restrict__ Ahi, const _Float16* __restrict__ Alo,
    const _Float16* __restrict__ Wp,
    const float* __restrict__ AL, const float* __restrict__ AR,
    __half2* __restrict__ feat2, float2* __restrict__ el2, float2* __restrict__ er2,
    int N) {
    constexpr int KC = 2, NT = 8;
    int wave = threadIdx.x >> 6, lane = threadIdx.x & 63;
    int mtile = blockIdx.x * 4 + wave;
    if (mtile * 16 >= N) return;
    int m0 = mtile * 16;
    int c = lane & 15, q = lane >> 4;
    v4f acc[NT];
#pragma unroll
    for (int t = 0; t < NT; t++) acc[t] = (v4f){0.f, 0.f, 0.f, 0.f};
    const size_t arow = (size_t)(m0 + c) * 64 + q * 8;
#pragma unroll
    for (int kc = 0; kc < KC; kc++) {
        half8 ah = *(const half8*)(Ahi + arow + kc * 32);
        half8 av = *(const half8*)(Alo + arow + kc * 32);
#pragma unroll
        for (int t = 0; t < NT; t++) {
            half8 b = *(const half8*)(Wp + ((size_t)(t * KC + kc) * 64 + lane) * 8);
            acc[t] = __builtin_amdgcn_mfma_f32_16x16x32_f16(ah, b, acc[t], 0, 0, 0);
            acc[t] = __builtin_amdgcn_mfma_f32_16x16x32_f16(av, b, acc[t], 0, 0, 0);
        }
    }
#pragma unroll
    for (int t = 0; t < NT / 2; t++)
#pragma unroll
        for (int r = 0; r < 4; r++) {
            int row = m0 + q * 4 + r;
            feat2[(size_t)row * 64 + t * 16 + c] =
                __floats2half2_rn(acc[t][r], acc[t + NT / 2][r]);
        }
    float alv[NT], arv[NT];
#pragma unroll
    for (int t = 0; t < NT; t++) { alv[t] = AL[t * 16 + c]; arv[t] = AR[t * 16 + c]; }
#pragma unroll
    for (int r = 0; r < 4; r++) {
        float l0 = 0.f, l1 = 0.f, r0 = 0.f, r1 = 0.f;
#pragma unroll
        for (int t = 0; t < NT; t++) {
            float v = acc[t][r];
            if (t < NT / 2) { l0 = fmaf(v, alv[t], l0); r0 = fmaf(v, arv[t], r0); }
            else            { l1 = fmaf(v, alv[t], l1); r1 = fmaf(v, arv[t], r1); }
        }
#pragma unroll
        for (int m = 1; m < 16; m <<= 1) {
            l0 += __shfl_xor(l0, m, 64);
            l1 += __shfl_xor(l1, m, 64);
            r0 += __shfl_xor(r0, m, 64);
            r1 += __shfl_xor(r1, m, 64);
        }
        if (c == 0) {
            int row = m0 + q * 4 + r;
            el2[row] = make_float2(l0, l1);
            er2[row] = make_float2(r0, r1);
        }
    }
}

// ---------------- agg2 PAIRED + split staging; mean over heads ----------------
__global__ __launch_bounds__(256) void aggregate64_mean(
    const int2* __restrict__ rowse, const int* __restrict__ csrc,
    const float2* __restrict__ el2, const float2* __restrict__ er2,
    const __half2* __restrict__ feat2, const float* __restrict__ b,
    float* __restrict__ out, int N) {
    __shared__ __attribute__((aligned(16))) int   stS0[4][64], stS1[4][64];
    __shared__ __attribute__((aligned(16))) float stX0[4][64], stY0[4][64];
    __shared__ __attribute__((aligned(16))) float stX1[4][64], stY1[4][64];
    int wave = threadIdx.x >> 6, lane = threadIdx.x & 63;
    int g = rfl(blockIdx.x * 4 + wave);
    int n0 = 2 * g, n1 = n0 + 1;
    if (n0 >= N) return;
    bool has1 = (n1 < N);
    float b0v = b[lane], b1v = b[64 + lane];
    int2 se0 = rowse[n0];
    int2 se1 = has1 ? rowse[n1] : make_int2(0, 0);
    int beg0 = rfl(se0.x), len0 = rfl(se0.y) - beg0;
    int beg1 = rfl(se1.x), len1 = rfl(se1.y) - beg1;
    float2 rr0 = er2[n0];
    float2 rr1 = has1 ? er2[n1] : make_float2(0.f, 0.f);
    const int* stSw0 = stS0[wave];
    const int* stSw1 = stS1[wave];
    float s00 = 0.f, s01 = 0.f, a00 = 0.f, a01 = 0.f;
    float s10 = 0.f, s11 = 0.f, a10 = 0.f, a11 = 0.f;
    int chunks = max(len0, len1);
    for (int off = 0; off < chunks; off += 64) {
        bool a0 = off + lane < len0;
        bool a1 = off + lane < len1;
        int sv0 = a0 ? csrc[beg0 + off + lane] : 0;
        int sv1 = a1 ? csrc[beg1 + off + lane] : 0;
        stS0[wave][lane] = sv0;
        stS1[wave][lane] = sv1;
        float wx0 = 0.f, wy0 = 0.f, wx1 = 0.f, wy1 = 0.f;
        if (a0) {
            float2 l = el2[sv0];
            float t0 = l.x + rr0.x; t0 = t0 > 0.f ? t0 : NEG_SLOPE * t0;
            float t1 = l.y + rr0.y; t1 = t1 > 0.f ? t1 : NEG_SLOPE * t1;
            wx0 = __expf(t0); wy0 = __expf(t1);
        }
        if (a1) {
            float2 l = el2[sv1];
            float t0 = l.x + rr1.x; t0 = t0 > 0.f ? t0 : NEG_SLOPE * t0;
            float t1 = l.y + rr1.y; t1 = t1 > 0.f ? t1 : NEG_SLOPE * t1;
            wx1 = __expf(t0); wy1 = __expf(t1);
        }
        stX0[wave][lane] = wx0; stY0[wave][lane] = wy0;
        stX1[wave][lane] = wx1; stY1[wave][lane] = wy1;
        int cnt = (min(64, chunks - off) + 7) & ~7;
        for (int j = 0; j < cnt; j += 8) {
            int4 sA = *(const int4*)(stSw0 + j);
            int4 sB = *(const int4*)(stSw0 + j + 4);
            int4 tA = *(const int4*)(stSw1 + j);
            int4 tB = *(const int4*)(stSw1 + j + 4);
            float2 fv0[8], fv1[8];
            fv0[0] = __half22float2(feat2[(size_t)sA.x * 64 + lane]);
            fv0[1] = __half22float2(feat2[(size_t)sA.y * 64 + lane]);
            fv0[2] = __half22float2(feat2[(size_t)sA.z * 64 + lane]);
            fv0[3] = __half22float2(feat2[(size_t)sA.w * 64 + lane]);
            fv0[4] = __half22float2(feat2[(size_t)sB.x * 64 + lane]);
            fv0[5] = __half22float2(feat2[(size_t)sB.y * 64 + lane]);
            fv0[6] = __half22float2(feat2[(size_t)sB.z * 64 + lane]);
            fv0[7] = __half22float2(feat2[(size_t)sB.w * 64 + lane]);
            fv1[0] = __half22float2(feat2[(size_t)tA.x * 64 + lane]);
            fv1[1] = __half22float2(feat2[(size_t)tA.y * 64 + lane]);
            fv1[2] = __half22float2(feat2[(size_t)tA.z * 64 + lane]);
            fv1[3] = __half22float2(feat2[(size_t)tA.w * 64 + lane]);
            fv1[4] = __half22float2(feat2[(size_t)tB.x * 64 + lane]);
            fv1[5] = __half22float2(feat2[(size_t)tB.y * 64 + lane]);
            fv1[6] = __half22float2(feat2[(size_t)tB.z * 64 + lane]);
            fv1[7] = __half22float2(feat2[(size_t)tB.w * 64 + lane]);
            float4 wx0v = *(const float4*)(stX0[wave] + j);
            float4 wx0w = *(const float4*)(stX0[wave] + j + 4);
            float4 wy0v = *(const float4*)(stY0[wave] + j);
            float4 wy0w = *(const float4*)(stY0[wave] + j + 4);
            float4 wx1v = *(const float4*)(stX1[wave] + j);
            float4 wx1w = *(const float4*)(stX1[wave] + j + 4);
            float4 wy1v = *(const float4*)(stY1[wave] + j);
            float4 wy1w = *(const float4*)(stY1[wave] + j + 4);
            float wxs0[8] = {wx0v.x, wx0v.y, wx0v.z, wx0v.w, wx0w.x, wx0w.y, wx0w.z, wx0w.w};
            float wys0[8] = {wy0v.x, wy0v.y, wy0v.z, wy0v.w, wy0w.x, wy0w.y, wy0w.z, wy0w.w};
            float wxs1[8] = {wx1v.x, wx1v.y, wx1v.z, wx1v.w, wx1w.x, wx1w.y, wx1w.z, wx1w.w};
            float wys1[8] = {wy1v.x, wy1v.y, wy1v.z, wy1v.w, wy1w.x, wy1w.y, wy1w.z, wy1w.w};
#pragma unroll
            for (int u = 0; u < 8; u++) {
                s00 += wxs0[u]; s01 += wys0[u];
                a00 = fmaf(wxs0[u], fv0[u].x, a00);
                a01 = fmaf(wys0[u], fv0[u].y, a01);
            }
#pragma unroll
            for (int u = 0; u < 8; u++) {
                s10 += wxs1[u]; s11 += wys1[u];
                a10 = fmaf(wxs1[u], fv1[u].x, a10);
                a11 = fmaf(wys1[u], fv1[u].y, a11);
            }
        }
    }
    float v0 = (s00 > 0.f) ? a00 / s00 : 0.f;
    float v1 = (s01 > 0.f) ? a01 / s01 : 0.f;
    out[(size_t)n0 * 64 + lane] = 0.5f * ((v0 + b0v) + (v1 + b1v));
    if (has1) {
        float u0 = (s10 > 0.f) ? a10 / s10 : 0.f;
        float u1 = (s11 > 0.f) ? a11 / s11 : 0.f;
        out[(size_t)n1 * 64 + lane] = 0.5f * ((u0 + b0v) + (u1 + b1v));
    }
}

// ---------------- launcher ----------------

extern "C" void kernel_launch(void* const* d_in, const int* in_sizes, int n_in,
                              void* d_out, int out_size, void* d_ws, size_t ws_size,
                              hipStream_t stream) {
    const float* x   = (const float*)d_in[0];
    const int*   src = (const int*)d_in[1];
    const int*   dst = (const int*)d_in[2];
    const float* W0  = (const float*)d_in[3];
    const float* al0 = (const float*)d_in[4];
    const float* ar0 = (const float*)d_in[5];
    const float* b0  = (const float*)d_in[6];
    const float* W1  = (const float*)d_in[7];
    const float* al1 = (const float*)d_in[8];
    const float* ar1 = (const float*)d_in[9];
    const float* b1  = (const float*)d_in[10];
    const float* W2  = (const float*)d_in[11];
    const float* al2 = (const float*)d_in[12];
    const float* ar2 = (const float*)d_in[13];
    const float* b2  = (const float*)d_in[14];
    float* out = (float*)d_out;

    const int N = NNODES;
    const int E = in_sizes[1];

    char* p = (char*)d_ws;
    auto alloc = [&](size_t bytes) {
        void* r = (void*)p;
        p += (bytes + 255) & ~(size_t)255;
        return r;
    };
    int*    bcursor = (int*)alloc((size_t)NBKT * 16 * 4);
    int2*   rowse   = (int2*)alloc((size_t)N * 8);
    int2*   ebuf    = (int2*)alloc(((size_t)NBKT * STRIDE + 4096) * 8);
    int*    csrc    = (int*)alloc(((size_t)NBKT * STRIDE + 4096) * 4);
    float2* el2A    = (float2*)alloc((size_t)N * 8);
    float2* er2A    = (float2*)alloc((size_t)N * 8);
    float2* el2B    = (float2*)alloc((size_t)N * 8);
    float2* er2B    = (float2*)alloc((size_t)N * 8);
    _Float16* ahi   = (_Float16*)alloc((size_t)N * 64 * 2);
    _Float16* alo   = (_Float16*)alloc((size_t)N * 64 * 2);
    _Float16* vhi0  = (_Float16*)alloc((size_t)N * 64 * 2);
    _Float16* vlo0  = (_Float16*)alloc((size_t)N * 64 * 2);
    void*   featA   = alloc((size_t)N * 64 * 4);
    _Float16* featB = (_Float16*)alloc((size_t)N * 64 * 2);
    _Float16* Wp2   = (_Float16*)alloc(8 * 2 * 64 * 8 * 2);
    _Float16* Wp1   = (_Float16*)alloc(4 * 2 * 64 * 8 * 2);

    // 0) zero bucket counters (partition counts from zero)
    hipMemsetAsync(bcursor, 0, (size_t)NBKT * 16 * 4, stream);
    // 1) gemm0 (LDS-packed W0) + pack W2 + pack W1 + partition, one launch
    int nch = (E + PCHUNK - 1) / PCHUNK;
    kernelAB<<<788 + nch, 256, 0, stream>>>(x, W0, al0, ar0, (_Float16*)featA, el2A, er2A,
                                            W2, Wp2, W1, Wp1, src, dst, bcursor, ebuf, E, N);
    // 2) local sort -> rowse + csrc (1024 threads/bucket)
    local_sort<<<NBKT, 1024, 0, stream>>>(ebuf, bcursor, rowse, csrc, N);

    int npair = (N + 1) / 2;
    int nbp = (npair + 3) / 4;
    int gb = (N / 16 + 3) / 4;
    // 3) layer-0 aggregate (PAIRED, split-stage) -> hi/lo fp16
    aggregate32<<<nbp, 256, 0, stream>>>(rowse, csrc, el2A, er2A, (const _Float16*)featA,
                                         b0, vhi0, vlo0, N);
    // 4) gemm1 MFMA (64->64) + layer-1 logits
    gemm_mfma1<<<gb, 256, 0, stream>>>(vhi0, vlo0, Wp1, al1, ar1, featB, el2B, er2B, N);
    // 5) layer-1 aggregate (PAIRED, split-stage) -> hi/lo fp16
    aggregate32<<<nbp, 256, 0, stream>>>(rowse, csrc, el2B, er2B, featB, b1, ahi, alo, N);
    // 6) gemm2 MFMA (64->128) + layer-2 logits
    gemm_mfma2<<<gb, 256, 0, stream>>>(ahi, alo, Wp2, al2, ar2, (__half2*)featA, el2A, er2A, N);
    // 7) layer-2 aggregate (PAIRED, split-stage), mean over heads
    aggregate64_mean<<<nbp, 256, 0, stream>>>(rowse, csrc, el2A, er2A, (const __half2*)featA,
                                              b2, out, N);
}